// Round 1
// baseline (3492.418 us; speedup 1.0000x reference)
//
#include <hip/hip_runtime.h>
#include <math.h>

#define B_ 16
#define INC 512
#define OUTC 256
#define FD 1024
#define DK 128
#define T_ 14
#define HO 64
#define WO 64
#define SP (HO*WO)

__device__ __forceinline__ float phi_f(float t) {
    return t > 0.0f ? t + 1.0f : expf(t);
}

// ---------------- K1: projections q/kl/kr = phi(X @ W), NN GEMM M=512 N=128 K=1024
__global__ __launch_bounds__(256) void k1_proj(const float* __restrict__ x,
        const float* __restrict__ wq, const float* __restrict__ wkl, const float* __restrict__ wkr,
        float* __restrict__ qbuf, float* __restrict__ klbuf, float* __restrict__ krbuf) {
    int z = blockIdx.z;
    int t = z / 3, which = z % 3;
    int src = (which == 0) ? (t + 1) : (which == 1 ? t : (t + 2));
    const float* A = x + (size_t)src * INC * FD;
    const float* Wp = (which == 0) ? wq : (which == 1 ? wkl : wkr);
    float* outP = ((which == 0) ? qbuf : (which == 1 ? klbuf : krbuf)) + t * INC * DK;

    __shared__ float As[32][68];
    __shared__ float Bs[32][68];
    int m0 = blockIdx.y * 64;
    int n0 = blockIdx.x * 64;
    int tid = threadIdx.y * 16 + threadIdx.x;
    float acc[4][4] = {};

    for (int kb = 0; kb < FD; kb += 32) {
        #pragma unroll
        for (int it = 0; it < 8; ++it) {
            int e = tid + it * 256;
            int m = e >> 5, kk = e & 31;
            As[kk][m] = A[(m0 + m) * FD + kb + kk];
        }
        #pragma unroll
        for (int it = 0; it < 8; ++it) {
            int e = tid + it * 256;
            int kk = e >> 6, n = e & 63;
            Bs[kk][n] = Wp[(kb + kk) * DK + n0 + n];
        }
        __syncthreads();
        #pragma unroll
        for (int kk = 0; kk < 32; ++kk) {
            float4 a4 = *(const float4*)&As[kk][threadIdx.y * 4];
            float4 b4 = *(const float4*)&Bs[kk][threadIdx.x * 4];
            float av[4] = {a4.x, a4.y, a4.z, a4.w};
            float bv[4] = {b4.x, b4.y, b4.z, b4.w};
            #pragma unroll
            for (int i = 0; i < 4; ++i)
                #pragma unroll
                for (int j = 0; j < 4; ++j)
                    acc[i][j] = fmaf(av[i], bv[j], acc[i][j]);
        }
        __syncthreads();
    }
    #pragma unroll
    for (int i = 0; i < 4; ++i) {
        int m = m0 + threadIdx.y * 4 + i;
        #pragma unroll
        for (int j = 0; j < 4; ++j) {
            int n = n0 + threadIdx.x * 4 + j;
            outP[m * DK + n] = phi_f(acc[i][j]);
        }
    }
}

// ---------------- K2: kv = K^T @ V, TN GEMM M=128 N=1024 K=512
__global__ __launch_bounds__(256) void k2_kv(const float* __restrict__ x,
        const float* __restrict__ klbuf, const float* __restrict__ krbuf,
        float* __restrict__ kvl, float* __restrict__ kvr) {
    int z = blockIdx.z;
    int t = z >> 1, side = z & 1;
    const float* A = (side == 0 ? klbuf : krbuf) + t * INC * DK;      // (512 x 128)
    const float* Bm = x + (size_t)(side == 0 ? t : t + 2) * INC * FD; // (512 x 1024)
    float* C = (side == 0 ? kvl : kvr) + t * DK * FD;

    __shared__ float As[32][68];
    __shared__ float Bs[32][68];
    int m0 = blockIdx.y * 64;
    int n0 = blockIdx.x * 64;
    int tid = threadIdx.y * 16 + threadIdx.x;
    float acc[4][4] = {};
    for (int kb = 0; kb < INC; kb += 32) {
        #pragma unroll
        for (int it = 0; it < 8; ++it) {
            int e = tid + it * 256;
            int kk = e >> 6, mn = e & 63;
            As[kk][mn] = A[(kb + kk) * DK + m0 + mn];
            Bs[kk][mn] = Bm[(kb + kk) * FD + n0 + mn];
        }
        __syncthreads();
        #pragma unroll
        for (int kk = 0; kk < 32; ++kk) {
            float4 a4 = *(const float4*)&As[kk][threadIdx.y * 4];
            float4 b4 = *(const float4*)&Bs[kk][threadIdx.x * 4];
            float av[4] = {a4.x, a4.y, a4.z, a4.w};
            float bv[4] = {b4.x, b4.y, b4.z, b4.w};
            #pragma unroll
            for (int i = 0; i < 4; ++i)
                #pragma unroll
                for (int j = 0; j < 4; ++j)
                    acc[i][j] = fmaf(av[i], bv[j], acc[i][j]);
        }
        __syncthreads();
    }
    #pragma unroll
    for (int i = 0; i < 4; ++i) {
        int m = m0 + threadIdx.y * 4 + i;
        #pragma unroll
        for (int j = 0; j < 4; ++j) {
            int n = n0 + threadIdx.x * 4 + j;
            C[m * FD + n] = acc[i][j];
        }
    }
}

// ---------------- K2b: ksum[k] = sum_n K[n,k]
__global__ void k2b_ksum(const float* __restrict__ klbuf, const float* __restrict__ krbuf,
                         float* __restrict__ ksuml, float* __restrict__ ksumr) {
    int t = blockIdx.x; int k = threadIdx.x;
    const float* Pl = klbuf + t * INC * DK;
    const float* Pr = krbuf + t * INC * DK;
    float s1 = 0.f, s2 = 0.f;
    for (int n = 0; n < INC; ++n) { s1 += Pl[n * DK + k]; s2 += Pr[n * DK + k]; }
    ksuml[t * DK + k] = s1; ksumr[t * DK + k] = s2;
}

// ---------------- K2c: z[n] = q[n,:].ksum + 1e-6
__global__ void k2c_z(const float* __restrict__ qbuf, const float* __restrict__ ksuml,
                      const float* __restrict__ ksumr, float* __restrict__ zl, float* __restrict__ zr) {
    int t = blockIdx.x; int n = threadIdx.x;
    const float* q = qbuf + (t * INC + n) * DK;
    const float* sl = ksuml + t * DK;
    const float* sr = ksumr + t * DK;
    float a = 0.f, b = 0.f;
    for (int k = 0; k < DK; ++k) { float qv = q[k]; a = fmaf(qv, sl[k], a); b = fmaf(qv, sr[k], b); }
    zl[t * INC + n] = a + 1e-6f;
    zr[t * INC + n] = b + 1e-6f;
}

// ---------------- K3: mid = x + (q@kvl)/zl + (q@kvr)/zr, dual NN GEMM M=512 N=1024 K=128
__global__ __launch_bounds__(256) void k3_out(const float* __restrict__ x,
        const float* __restrict__ qbuf, const float* __restrict__ kvl, const float* __restrict__ kvr,
        const float* __restrict__ zl, const float* __restrict__ zr, float* __restrict__ newbuf) {
    int t = blockIdx.z;
    const float* A  = qbuf + t * INC * DK;
    const float* B1 = kvl + t * DK * FD;
    const float* B2 = kvr + t * DK * FD;
    __shared__ float As[32][68];
    __shared__ float B1s[32][68];
    __shared__ float B2s[32][68];
    int m0 = blockIdx.y * 64, n0 = blockIdx.x * 64;
    int tid = threadIdx.y * 16 + threadIdx.x;
    float acc1[4][4] = {}, acc2[4][4] = {};
    for (int kb = 0; kb < DK; kb += 32) {
        #pragma unroll
        for (int it = 0; it < 8; ++it) {
            int e = tid + it * 256;
            int m = e >> 5, kk = e & 31;
            As[kk][m] = A[(m0 + m) * DK + kb + kk];
        }
        #pragma unroll
        for (int it = 0; it < 8; ++it) {
            int e = tid + it * 256;
            int kk = e >> 6, n = e & 63;
            B1s[kk][n] = B1[(kb + kk) * FD + n0 + n];
            B2s[kk][n] = B2[(kb + kk) * FD + n0 + n];
        }
        __syncthreads();
        #pragma unroll
        for (int kk = 0; kk < 32; ++kk) {
            float4 a4 = *(const float4*)&As[kk][threadIdx.y * 4];
            float4 b4 = *(const float4*)&B1s[kk][threadIdx.x * 4];
            float4 c4 = *(const float4*)&B2s[kk][threadIdx.x * 4];
            float av[4] = {a4.x, a4.y, a4.z, a4.w};
            float bv[4] = {b4.x, b4.y, b4.z, b4.w};
            float cv[4] = {c4.x, c4.y, c4.z, c4.w};
            #pragma unroll
            for (int i = 0; i < 4; ++i)
                #pragma unroll
                for (int j = 0; j < 4; ++j) {
                    acc1[i][j] = fmaf(av[i], bv[j], acc1[i][j]);
                    acc2[i][j] = fmaf(av[i], cv[j], acc2[i][j]);
                }
        }
        __syncthreads();
    }
    const float* xc = x + (size_t)(t + 1) * INC * FD;
    float* outp = newbuf + (size_t)t * INC * FD;
    #pragma unroll
    for (int i = 0; i < 4; ++i) {
        int n = m0 + threadIdx.y * 4 + i;
        float invl = 1.0f / zl[t * INC + n];
        float invr = 1.0f / zr[t * INC + n];
        #pragma unroll
        for (int j = 0; j < 4; ++j) {
            int d = n0 + threadIdx.x * 4 + j;
            outp[n * FD + d] = xc[n * FD + d] + acc1[i][j] * invl + acc2[i][j] * invr;
        }
    }
}

// ---------------- K4: upconv (TN GEMM M=1024 N=1024 K=512) + gate, writes gbuf
__global__ __launch_bounds__(256) void k4_up(const float* __restrict__ x,
        const float* __restrict__ newbuf, const float* __restrict__ up_w,
        const float* __restrict__ up_b, const float* __restrict__ s_in,
        float* __restrict__ gbuf) {
    int b = blockIdx.z;
    const float* Bm = (b == 0) ? x
                    : (b == B_ - 1) ? (x + (size_t)(B_ - 1) * INC * FD)
                    : (newbuf + (size_t)(b - 1) * INC * FD);
    __shared__ float As[32][68];
    __shared__ float Bs[32][68];
    int m0 = blockIdx.y * 64, n0 = blockIdx.x * 64;
    int tid = threadIdx.y * 16 + threadIdx.x;
    float acc[4][4] = {};
    for (int kb = 0; kb < INC; kb += 32) {
        #pragma unroll
        for (int it = 0; it < 8; ++it) {
            int e = tid + it * 256;
            int kk = e >> 6, mn = e & 63;
            As[kk][mn] = up_w[(kb + kk) * 1024 + m0 + mn];
            Bs[kk][mn] = Bm[(kb + kk) * FD + n0 + mn];
        }
        __syncthreads();
        #pragma unroll
        for (int kk = 0; kk < 32; ++kk) {
            float4 a4 = *(const float4*)&As[kk][threadIdx.y * 4];
            float4 b4 = *(const float4*)&Bs[kk][threadIdx.x * 4];
            float av[4] = {a4.x, a4.y, a4.z, a4.w};
            float bv[4] = {b4.x, b4.y, b4.z, b4.w};
            #pragma unroll
            for (int i = 0; i < 4; ++i)
                #pragma unroll
                for (int j = 0; j < 4; ++j)
                    acc[i][j] = fmaf(av[i], bv[j], acc[i][j]);
        }
        __syncthreads();
    }
    #pragma unroll
    for (int i = 0; i < 4; ++i) {
        int m = m0 + threadIdx.y * 4 + i;
        int o = m >> 2, aa = (m >> 1) & 1, cb = m & 1;
        float bias = up_b[o];
        #pragma unroll
        for (int j = 0; j < 4; ++j) {
            int ij = n0 + threadIdx.x * 4 + j;
            int ii = ij >> 5, jj = ij & 31;
            int p = 2 * ii + aa, q = 2 * jj + cb;
            size_t idx = ((size_t)(b * OUTC + o) * HO + p) * WO + q;
            float up = acc[i][j] + bias;
            float r = fmaxf(up + s_in[idx], 0.0f);
            gbuf[idx] = 1.0f / (1.0f + expf(-r));
        }
    }
}

// ---------------- K5: direct conv 3x3 (512->256) + bias, writes pre-BN y to d_out
#define CCH 8
__global__ __launch_bounds__(256) void k5_conv(const float* __restrict__ gbuf,
        const float* __restrict__ s_in, const float* __restrict__ c1_w,
        const float* __restrict__ c1_b, float* __restrict__ y) {
    __shared__ float patch[CCH * 34 * 34];
    __shared__ float wl[CCH * 9 * 16];
    int b = blockIdx.z;
    int o0 = blockIdx.y * 16;
    int py0 = (blockIdx.x >> 1) * 32, qx0 = (blockIdx.x & 1) * 32;
    int tid = threadIdx.x;
    int yy = tid >> 3;
    int x4 = (tid & 7) * 4;
    float acc[16][4] = {};
    for (int cc = 0; cc < 2 * OUTC; cc += CCH) {
        const float* src = (cc < OUTC) ? (gbuf + ((size_t)b * OUTC + cc) * SP)
                                       : (s_in + ((size_t)b * OUTC + (cc - OUTC)) * SP);
        for (int idx = tid; idx < CCH * 34 * 34; idx += 256) {
            int c_l = idx / 1156; int rem = idx - c_l * 1156;
            int r = rem / 34; int col = rem - r * 34;
            int gy = py0 + r - 1, gx = qx0 + col - 1;
            float v = 0.0f;
            if (gy >= 0 && gy < HO && gx >= 0 && gx < WO)
                v = src[c_l * SP + gy * WO + gx];
            patch[idx] = v;
        }
        for (int idx = tid; idx < CCH * 9 * 16; idx += 256) {
            int o_l = idx & 15; int ct = idx >> 4;
            int c_l = ct / 9; int tap = ct - c_l * 9;
            wl[idx] = c1_w[(o0 + o_l) * (2 * OUTC * 9) + (cc + c_l) * 9 + tap];
        }
        __syncthreads();
        #pragma unroll
        for (int c_l = 0; c_l < CCH; ++c_l) {
            #pragma unroll
            for (int dy = 0; dy < 3; ++dy) {
                const float* rowp = &patch[c_l * 1156 + (yy + dy) * 34 + x4];
                float in6[6];
                #pragma unroll
                for (int i2 = 0; i2 < 6; ++i2) in6[i2] = rowp[i2];
                #pragma unroll
                for (int dx = 0; dx < 3; ++dx) {
                    const float4* wp4 = (const float4*)&wl[(c_l * 9 + dy * 3 + dx) * 16];
                    float4 w0 = wp4[0], w1 = wp4[1], w2 = wp4[2], w3 = wp4[3];
                    float wv[16] = {w0.x, w0.y, w0.z, w0.w, w1.x, w1.y, w1.z, w1.w,
                                    w2.x, w2.y, w2.z, w2.w, w3.x, w3.y, w3.z, w3.w};
                    #pragma unroll
                    for (int o = 0; o < 16; ++o)
                        #pragma unroll
                        for (int m = 0; m < 4; ++m)
                            acc[o][m] = fmaf(wv[o], in6[dx + m], acc[o][m]);
                }
            }
        }
        __syncthreads();
    }
    #pragma unroll
    for (int o = 0; o < 16; ++o) {
        float bias = c1_b[o0 + o];
        float4 v;
        v.x = acc[o][0] + bias; v.y = acc[o][1] + bias;
        v.z = acc[o][2] + bias; v.w = acc[o][3] + bias;
        *(float4*)&y[(((size_t)b * OUTC + o0 + o) * HO + py0 + yy) * WO + qx0 + x4] = v;
    }
}

// ---------------- K6: BN stats reduce
__global__ __launch_bounds__(256) void k6_bnred(const float* __restrict__ y,
        float* __restrict__ bnsum, float* __restrict__ bnsq) {
    int b = blockIdx.x, o = blockIdx.y;
    const float* p = y + ((size_t)b * OUTC + o) * SP;
    float s1 = 0.f, s2 = 0.f;
    for (int i = threadIdx.x; i < SP; i += 256) { float v = p[i]; s1 += v; s2 = fmaf(v, v, s2); }
    #pragma unroll
    for (int off = 32; off > 0; off >>= 1) {
        s1 += __shfl_down(s1, off, 64);
        s2 += __shfl_down(s2, off, 64);
    }
    __shared__ float r1[4], r2[4];
    int wid = threadIdx.x >> 6, lane = threadIdx.x & 63;
    if (lane == 0) { r1[wid] = s1; r2[wid] = s2; }
    __syncthreads();
    if (threadIdx.x == 0) {
        atomicAdd(&bnsum[o], r1[0] + r1[1] + r1[2] + r1[3]);
        atomicAdd(&bnsq[o],  r2[0] + r2[1] + r2[2] + r2[3]);
    }
}

// ---------------- K7: BN finalize
__global__ void k7_bnfin(const float* __restrict__ bnsum, const float* __restrict__ bnsq,
                         const float* __restrict__ bn_g, const float* __restrict__ bn_b,
                         float* __restrict__ scale, float* __restrict__ shift) {
    int o = threadIdx.x;
    float cnt = (float)(B_ * SP);
    float mu = bnsum[o] / cnt;
    float var = bnsq[o] / cnt - mu * mu;
    float sc = bn_g[o] * rsqrtf(var + 1e-5f);
    scale[o] = sc;
    shift[o] = bn_b[o] - mu * sc;
}

// ---------------- K8: BN apply + relu, in place on d_out
__global__ __launch_bounds__(256) void k8_apply(float* __restrict__ y,
        const float* __restrict__ scale, const float* __restrict__ shift) {
    int i = blockIdx.x * 256 + threadIdx.x;      // float4 index
    int o = (i >> 10) & 255;
    float4 v = ((float4*)y)[i];
    float sc = scale[o], sh = shift[o];
    v.x = fmaxf(fmaf(v.x, sc, sh), 0.f);
    v.y = fmaxf(fmaf(v.y, sc, sh), 0.f);
    v.z = fmaxf(fmaf(v.z, sc, sh), 0.f);
    v.w = fmaxf(fmaf(v.w, sc, sh), 0.f);
    ((float4*)y)[i] = v;
}

extern "C" void kernel_launch(void* const* d_in, const int* in_sizes, int n_in,
                              void* d_out, int out_size, void* d_ws, size_t ws_size,
                              hipStream_t stream) {
    const float* x    = (const float*)d_in[0];
    const float* s_in = (const float*)d_in[1];
    const float* up_w = (const float*)d_in[2];
    const float* up_b = (const float*)d_in[3];
    const float* wq   = (const float*)d_in[4];
    const float* wkl  = (const float*)d_in[5];
    const float* wkr  = (const float*)d_in[6];
    const float* c1_w = (const float*)d_in[7];
    const float* c1_b = (const float*)d_in[8];
    const float* bn_g = (const float*)d_in[9];
    const float* bn_b = (const float*)d_in[10];
    float* y = (float*)d_out;
    float* ws = (float*)d_ws;

    size_t off = 0;
    float* qbuf  = ws + off; off += (size_t)T_ * INC * DK;
    float* klbuf = ws + off; off += (size_t)T_ * INC * DK;
    float* krbuf = ws + off; off += (size_t)T_ * INC * DK;
    float* kvl   = ws + off; off += (size_t)T_ * DK * FD;
    float* kvr   = ws + off; off += (size_t)T_ * DK * FD;
    float* ksuml = ws + off; off += (size_t)T_ * DK;
    float* ksumr = ws + off; off += (size_t)T_ * DK;
    float* zl    = ws + off; off += (size_t)T_ * INC;
    float* zr    = ws + off; off += (size_t)T_ * INC;
    float* newbuf= ws + off; off += (size_t)T_ * INC * FD;
    float* gbuf  = ws + off; off += (size_t)B_ * OUTC * SP;
    float* bnsum = ws + off; off += OUTC;
    float* bnsq  = ws + off; off += OUTC;
    float* scale = ws + off; off += OUTC;
    float* shift = ws + off; off += OUTC;

    hipMemsetAsync(bnsum, 0, 2 * OUTC * sizeof(float), stream);

    dim3 thr(16, 16);
    k1_proj<<<dim3(2, 8, 42), thr, 0, stream>>>(x, wq, wkl, wkr, qbuf, klbuf, krbuf);
    k2_kv<<<dim3(16, 2, 28), thr, 0, stream>>>(x, klbuf, krbuf, kvl, kvr);
    k2b_ksum<<<dim3(T_), dim3(DK), 0, stream>>>(klbuf, krbuf, ksuml, ksumr);
    k2c_z<<<dim3(T_), dim3(INC), 0, stream>>>(qbuf, ksuml, ksumr, zl, zr);
    k3_out<<<dim3(16, 8, T_), thr, 0, stream>>>(x, qbuf, kvl, kvr, zl, zr, newbuf);
    k4_up<<<dim3(16, 16, B_), thr, 0, stream>>>(x, newbuf, up_w, up_b, s_in, gbuf);
    k5_conv<<<dim3(4, 16, B_), dim3(256), 0, stream>>>(gbuf, s_in, c1_w, c1_b, y);
    k6_bnred<<<dim3(B_, OUTC), dim3(256), 0, stream>>>(y, bnsum, bnsq);
    k7_bnfin<<<dim3(1), dim3(OUTC), 0, stream>>>(bnsum, bnsq, bn_g, bn_b, scale, shift);
    k8_apply<<<dim3((B_ * OUTC * SP / 4) / 256), dim3(256), 0, stream>>>(y, scale, shift);
}

// Round 2
// 961.238 us; speedup vs baseline: 3.6333x; 3.6333x over previous
//
#include <hip/hip_runtime.h>
#include <math.h>

#define B_ 16
#define INC 512
#define OUTC 256
#define FD 1024
#define DK 128
#define T_ 14
#define HO 64
#define WO 64
#define SP (HO*WO)
#define KCP 40   // padded channel stride in conv LDS slab (80 B: <=2-way bank alias, free)

typedef unsigned short u16;
typedef __attribute__((ext_vector_type(8))) short shortx8;
typedef __attribute__((ext_vector_type(4))) float floatx4;

__device__ __forceinline__ float phi_f(float t) {
    return t > 0.0f ? t + 1.0f : expf(t);
}
__device__ __forceinline__ u16 f2bf(float f) {
    unsigned int u = __float_as_uint(f);
    unsigned int r = (u + 0x7fffu + ((u >> 16) & 1u)) >> 16;
    return (u16)r;
}

// ---------------- K1: projections q/kl/kr = phi(X @ W), NN GEMM M=512 N=128 K=1024
__global__ __launch_bounds__(256) void k1_proj(const float* __restrict__ x,
        const float* __restrict__ wq, const float* __restrict__ wkl, const float* __restrict__ wkr,
        float* __restrict__ qbuf, float* __restrict__ klbuf, float* __restrict__ krbuf) {
    int z = blockIdx.z;
    int t = z / 3, which = z % 3;
    int src = (which == 0) ? (t + 1) : (which == 1 ? t : (t + 2));
    const float* A = x + (size_t)src * INC * FD;
    const float* Wp = (which == 0) ? wq : (which == 1 ? wkl : wkr);
    float* outP = ((which == 0) ? qbuf : (which == 1 ? klbuf : krbuf)) + t * INC * DK;

    __shared__ float As[32][68];
    __shared__ float Bs[32][68];
    int m0 = blockIdx.y * 64;
    int n0 = blockIdx.x * 64;
    int tid = threadIdx.y * 16 + threadIdx.x;
    float acc[4][4] = {};

    for (int kb = 0; kb < FD; kb += 32) {
        #pragma unroll
        for (int it = 0; it < 8; ++it) {
            int e = tid + it * 256;
            int m = e >> 5, kk = e & 31;
            As[kk][m] = A[(m0 + m) * FD + kb + kk];
        }
        #pragma unroll
        for (int it = 0; it < 8; ++it) {
            int e = tid + it * 256;
            int kk = e >> 6, n = e & 63;
            Bs[kk][n] = Wp[(kb + kk) * DK + n0 + n];
        }
        __syncthreads();
        #pragma unroll
        for (int kk = 0; kk < 32; ++kk) {
            float4 a4 = *(const float4*)&As[kk][threadIdx.y * 4];
            float4 b4 = *(const float4*)&Bs[kk][threadIdx.x * 4];
            float av[4] = {a4.x, a4.y, a4.z, a4.w};
            float bv[4] = {b4.x, b4.y, b4.z, b4.w};
            #pragma unroll
            for (int i = 0; i < 4; ++i)
                #pragma unroll
                for (int j = 0; j < 4; ++j)
                    acc[i][j] = fmaf(av[i], bv[j], acc[i][j]);
        }
        __syncthreads();
    }
    #pragma unroll
    for (int i = 0; i < 4; ++i) {
        int m = m0 + threadIdx.y * 4 + i;
        #pragma unroll
        for (int j = 0; j < 4; ++j) {
            int n = n0 + threadIdx.x * 4 + j;
            outP[m * DK + n] = phi_f(acc[i][j]);
        }
    }
}

// ---------------- K2: kv = K^T @ V, TN GEMM M=128 N=1024 K=512
__global__ __launch_bounds__(256) void k2_kv(const float* __restrict__ x,
        const float* __restrict__ klbuf, const float* __restrict__ krbuf,
        float* __restrict__ kvl, float* __restrict__ kvr) {
    int z = blockIdx.z;
    int t = z >> 1, side = z & 1;
    const float* A = (side == 0 ? klbuf : krbuf) + t * INC * DK;
    const float* Bm = x + (size_t)(side == 0 ? t : t + 2) * INC * FD;
    float* C = (side == 0 ? kvl : kvr) + t * DK * FD;

    __shared__ float As[32][68];
    __shared__ float Bs[32][68];
    int m0 = blockIdx.y * 64;
    int n0 = blockIdx.x * 64;
    int tid = threadIdx.y * 16 + threadIdx.x;
    float acc[4][4] = {};
    for (int kb = 0; kb < INC; kb += 32) {
        #pragma unroll
        for (int it = 0; it < 8; ++it) {
            int e = tid + it * 256;
            int kk = e >> 6, mn = e & 63;
            As[kk][mn] = A[(kb + kk) * DK + m0 + mn];
            Bs[kk][mn] = Bm[(kb + kk) * FD + n0 + mn];
        }
        __syncthreads();
        #pragma unroll
        for (int kk = 0; kk < 32; ++kk) {
            float4 a4 = *(const float4*)&As[kk][threadIdx.y * 4];
            float4 b4 = *(const float4*)&Bs[kk][threadIdx.x * 4];
            float av[4] = {a4.x, a4.y, a4.z, a4.w};
            float bv[4] = {b4.x, b4.y, b4.z, b4.w};
            #pragma unroll
            for (int i = 0; i < 4; ++i)
                #pragma unroll
                for (int j = 0; j < 4; ++j)
                    acc[i][j] = fmaf(av[i], bv[j], acc[i][j]);
        }
        __syncthreads();
    }
    #pragma unroll
    for (int i = 0; i < 4; ++i) {
        int m = m0 + threadIdx.y * 4 + i;
        #pragma unroll
        for (int j = 0; j < 4; ++j) {
            int n = n0 + threadIdx.x * 4 + j;
            C[m * FD + n] = acc[i][j];
        }
    }
}

// ---------------- K2b: ksum[k] = sum_n K[n,k]
__global__ void k2b_ksum(const float* __restrict__ klbuf, const float* __restrict__ krbuf,
                         float* __restrict__ ksuml, float* __restrict__ ksumr) {
    int t = blockIdx.x; int k = threadIdx.x;
    const float* Pl = klbuf + t * INC * DK;
    const float* Pr = krbuf + t * INC * DK;
    float s1 = 0.f, s2 = 0.f;
    for (int n = 0; n < INC; ++n) { s1 += Pl[n * DK + k]; s2 += Pr[n * DK + k]; }
    ksuml[t * DK + k] = s1; ksumr[t * DK + k] = s2;
}

// ---------------- K2c: z[n] = q[n,:].ksum + 1e-6
__global__ void k2c_z(const float* __restrict__ qbuf, const float* __restrict__ ksuml,
                      const float* __restrict__ ksumr, float* __restrict__ zl, float* __restrict__ zr) {
    int t = blockIdx.x; int n = threadIdx.x;
    const float* q = qbuf + (t * INC + n) * DK;
    const float* sl = ksuml + t * DK;
    const float* sr = ksumr + t * DK;
    float a = 0.f, b = 0.f;
    for (int k = 0; k < DK; ++k) { float qv = q[k]; a = fmaf(qv, sl[k], a); b = fmaf(qv, sr[k], b); }
    zl[t * INC + n] = a + 1e-6f;
    zr[t * INC + n] = b + 1e-6f;
}

// ---------------- K3: mid = x + (q@kvl)/zl + (q@kvr)/zr
__global__ __launch_bounds__(256) void k3_out(const float* __restrict__ x,
        const float* __restrict__ qbuf, const float* __restrict__ kvl, const float* __restrict__ kvr,
        const float* __restrict__ zl, const float* __restrict__ zr, float* __restrict__ newbuf) {
    int t = blockIdx.z;
    const float* A  = qbuf + t * INC * DK;
    const float* B1 = kvl + t * DK * FD;
    const float* B2 = kvr + t * DK * FD;
    __shared__ float As[32][68];
    __shared__ float B1s[32][68];
    __shared__ float B2s[32][68];
    int m0 = blockIdx.y * 64, n0 = blockIdx.x * 64;
    int tid = threadIdx.y * 16 + threadIdx.x;
    float acc1[4][4] = {}, acc2[4][4] = {};
    for (int kb = 0; kb < DK; kb += 32) {
        #pragma unroll
        for (int it = 0; it < 8; ++it) {
            int e = tid + it * 256;
            int m = e >> 5, kk = e & 31;
            As[kk][m] = A[(m0 + m) * DK + kb + kk];
        }
        #pragma unroll
        for (int it = 0; it < 8; ++it) {
            int e = tid + it * 256;
            int kk = e >> 6, n = e & 63;
            B1s[kk][n] = B1[(kb + kk) * FD + n0 + n];
            B2s[kk][n] = B2[(kb + kk) * FD + n0 + n];
        }
        __syncthreads();
        #pragma unroll
        for (int kk = 0; kk < 32; ++kk) {
            float4 a4 = *(const float4*)&As[kk][threadIdx.y * 4];
            float4 b4 = *(const float4*)&B1s[kk][threadIdx.x * 4];
            float4 c4 = *(const float4*)&B2s[kk][threadIdx.x * 4];
            float av[4] = {a4.x, a4.y, a4.z, a4.w};
            float bv[4] = {b4.x, b4.y, b4.z, b4.w};
            float cv[4] = {c4.x, c4.y, c4.z, c4.w};
            #pragma unroll
            for (int i = 0; i < 4; ++i)
                #pragma unroll
                for (int j = 0; j < 4; ++j) {
                    acc1[i][j] = fmaf(av[i], bv[j], acc1[i][j]);
                    acc2[i][j] = fmaf(av[i], cv[j], acc2[i][j]);
                }
        }
        __syncthreads();
    }
    const float* xc = x + (size_t)(t + 1) * INC * FD;
    float* outp = newbuf + (size_t)t * INC * FD;
    #pragma unroll
    for (int i = 0; i < 4; ++i) {
        int n = m0 + threadIdx.y * 4 + i;
        float invl = 1.0f / zl[t * INC + n];
        float invr = 1.0f / zr[t * INC + n];
        #pragma unroll
        for (int j = 0; j < 4; ++j) {
            int d = n0 + threadIdx.x * 4 + j;
            outp[n * FD + d] = xc[n * FD + d] + acc1[i][j] * invl + acc2[i][j] * invr;
        }
    }
}

// ---------------- K4: upconv GEMM + gate, writes bf16 into padded P (channels 0..255)
__global__ __launch_bounds__(256) void k4_up(const float* __restrict__ x,
        const float* __restrict__ newbuf, const float* __restrict__ up_w,
        const float* __restrict__ up_b, const float* __restrict__ s_in,
        u16* __restrict__ P) {
    int b = blockIdx.z;
    const float* Bm = (b == 0) ? x
                    : (b == B_ - 1) ? (x + (size_t)(B_ - 1) * INC * FD)
                    : (newbuf + (size_t)(b - 1) * INC * FD);
    __shared__ float As[32][68];
    __shared__ float Bs[32][68];
    int m0 = blockIdx.y * 64, n0 = blockIdx.x * 64;
    int tid = threadIdx.y * 16 + threadIdx.x;
    float acc[4][4] = {};
    for (int kb = 0; kb < INC; kb += 32) {
        #pragma unroll
        for (int it = 0; it < 8; ++it) {
            int e = tid + it * 256;
            int kk = e >> 6, mn = e & 63;
            As[kk][mn] = up_w[(kb + kk) * 1024 + m0 + mn];
            Bs[kk][mn] = Bm[(kb + kk) * FD + n0 + mn];
        }
        __syncthreads();
        #pragma unroll
        for (int kk = 0; kk < 32; ++kk) {
            float4 a4 = *(const float4*)&As[kk][threadIdx.y * 4];
            float4 b4 = *(const float4*)&Bs[kk][threadIdx.x * 4];
            float av[4] = {a4.x, a4.y, a4.z, a4.w};
            float bv[4] = {b4.x, b4.y, b4.z, b4.w};
            #pragma unroll
            for (int i = 0; i < 4; ++i)
                #pragma unroll
                for (int j = 0; j < 4; ++j)
                    acc[i][j] = fmaf(av[i], bv[j], acc[i][j]);
        }
        __syncthreads();
    }
    #pragma unroll
    for (int i = 0; i < 4; ++i) {
        int m = m0 + threadIdx.y * 4 + i;
        int o = m >> 2, aa = (m >> 1) & 1, cb = m & 1;
        float bias = up_b[o];
        #pragma unroll
        for (int j = 0; j < 4; ++j) {
            int ij = n0 + threadIdx.x * 4 + j;
            int ii = ij >> 5, jj = ij & 31;
            int p = 2 * ii + aa, q = 2 * jj + cb;
            size_t sidx = ((size_t)(b * OUTC + o) * HO + p) * WO + q;
            float up = acc[i][j] + bias;
            float r = fmaxf(up + s_in[sidx], 0.0f);
            float g = 1.0f / (1.0f + expf(-r));
            P[((size_t)(b * 66 + 1 + p) * 66 + 1 + q) * 512 + o] = f2bf(g);
        }
    }
}

// ---------------- K4b: skip s -> bf16 into padded P (channels 256..511), LDS transpose
__global__ __launch_bounds__(256) void k4b_sfill(const float* __restrict__ s_in,
                                                 u16* __restrict__ P) {
    __shared__ u16 T[64 * 264];
    int p = blockIdx.x;   // output row 0..63
    int b = blockIdx.y;
    int tid = threadIdx.x;
    int qcol = tid & 63;
    int ob = tid >> 6;          // 0..3
    for (int o = ob; o < 256; o += 4) {
        float v = s_in[((size_t)(b * OUTC + o) * HO + p) * WO + qcol];
        T[qcol * 264 + o] = f2bf(v);
    }
    __syncthreads();
    int q2 = tid >> 2;          // 0..63
    int sg = tid & 3;
    size_t base = ((size_t)(b * 66 + 1 + p) * 66 + 1 + q2) * 512 + 256;
    #pragma unroll
    for (int it = 0; it < 8; ++it) {
        int seg = sg + it * 4;  // 0..31 (8 channels each)
        uint4 v = *(const uint4*)&T[q2 * 264 + seg * 8];
        *(uint4*)(P + base + seg * 8) = v;
    }
}

// ---------------- KW: transpose conv weights to Wt[tap][o][c] bf16
__global__ void kw_tr(const float* __restrict__ c1_w, u16* __restrict__ Wt) {
    int i = blockIdx.x * 256 + threadIdx.x;
    if (i >= 256 * 512 * 9) return;
    int tap = i % 9; int t2 = i / 9;
    int c = t2 % 512; int o = t2 / 512;
    Wt[((size_t)tap * 256 + o) * 512 + c] = f2bf(c1_w[i]);
}

// ---------------- K5: conv3x3 as MFMA implicit GEMM. wg = 4 rows x 64 cols x 64 o.
__global__ __launch_bounds__(256) void k5_mfma(const u16* __restrict__ P,
        const u16* __restrict__ Wt, const float* __restrict__ c1_b,
        float* __restrict__ y) {
    __shared__ u16 Xs[6 * 66 * KCP];
    int rb = blockIdx.x;        // 16 row-blocks (4 output rows each)
    int o0 = blockIdx.y * 64;   // 4 o-blocks
    int b  = blockIdx.z;
    int tid = threadIdx.x;
    int w = tid >> 6, lane = tid & 63;
    int l15 = lane & 15, quad = lane >> 4;

    floatx4 acc[4][4];
    #pragma unroll
    for (int i = 0; i < 4; ++i)
        #pragma unroll
        for (int j = 0; j < 4; ++j)
            acc[i][j] = (floatx4){0.f, 0.f, 0.f, 0.f};

    size_t Pbase = ((size_t)b * 66 + (size_t)rb * 4) * 66 * 512;

    for (int ch = 0; ch < 16; ++ch) {
        int c0 = ch * 32;
        __syncthreads();
        // stage 6 rows x 66 cols x 32 ch slab, transposed-to-[row][col][c] (already c-innermost)
        for (int s = tid; s < 1584; s += 256) {
            int r = s / 264; int rem = s - r * 264;
            int col = rem >> 2; int cs = rem & 3;
            uint4 v = *(const uint4*)(P + Pbase + ((size_t)r * 66 + col) * 512 + c0 + cs * 8);
            *(uint4*)&Xs[(r * 66 + col) * KCP + cs * 8] = v;
        }
        __syncthreads();
        #pragma unroll
        for (int dy = 0; dy < 3; ++dy) {
            #pragma unroll
            for (int dx = 0; dx < 3; ++dx) {
                int tap = dy * 3 + dx;
                shortx8 wf[4];
                #pragma unroll
                for (int nt = 0; nt < 4; ++nt)
                    wf[nt] = *(const shortx8*)(Wt +
                        ((size_t)(tap * 256 + o0 + nt * 16 + l15)) * 512 + c0 + quad * 8);
                #pragma unroll
                for (int mt = 0; mt < 4; ++mt) {
                    shortx8 af = *(const shortx8*)&Xs[((w + dy) * 66 + mt * 16 + l15 + dx) * KCP + quad * 8];
                    #pragma unroll
                    for (int nt = 0; nt < 4; ++nt)
                        acc[mt][nt] = __builtin_amdgcn_mfma_f32_16x16x32_bf16(
                            af, wf[nt], acc[mt][nt], 0, 0, 0);
                }
            }
        }
    }
    // epilogue: bias + store fp32 y
    int row = rb * 4 + w;
    float bias[4];
    #pragma unroll
    for (int nt = 0; nt < 4; ++nt) bias[nt] = c1_b[o0 + nt * 16 + l15];
    #pragma unroll
    for (int mt = 0; mt < 4; ++mt) {
        #pragma unroll
        for (int nt = 0; nt < 4; ++nt) {
            int o = o0 + nt * 16 + l15;
            size_t ybase = (size_t)(b * OUTC + o) * SP + row * 64;
            #pragma unroll
            for (int r = 0; r < 4; ++r) {
                int col = mt * 16 + quad * 4 + r;
                y[ybase + col] = acc[mt][nt][r] + bias[nt];
            }
        }
    }
}

// ---------------- K6: BN stats reduce
__global__ __launch_bounds__(256) void k6_bnred(const float* __restrict__ y,
        float* __restrict__ bnsum, float* __restrict__ bnsq) {
    int b = blockIdx.x, o = blockIdx.y;
    const float* p = y + ((size_t)b * OUTC + o) * SP;
    float s1 = 0.f, s2 = 0.f;
    for (int i = threadIdx.x; i < SP; i += 256) { float v = p[i]; s1 += v; s2 = fmaf(v, v, s2); }
    #pragma unroll
    for (int off = 32; off > 0; off >>= 1) {
        s1 += __shfl_down(s1, off, 64);
        s2 += __shfl_down(s2, off, 64);
    }
    __shared__ float r1[4], r2[4];
    int wid = threadIdx.x >> 6, lane = threadIdx.x & 63;
    if (lane == 0) { r1[wid] = s1; r2[wid] = s2; }
    __syncthreads();
    if (threadIdx.x == 0) {
        atomicAdd(&bnsum[o], r1[0] + r1[1] + r1[2] + r1[3]);
        atomicAdd(&bnsq[o],  r2[0] + r2[1] + r2[2] + r2[3]);
    }
}

// ---------------- K7: BN finalize
__global__ void k7_bnfin(const float* __restrict__ bnsum, const float* __restrict__ bnsq,
                         const float* __restrict__ bn_g, const float* __restrict__ bn_b,
                         float* __restrict__ scale, float* __restrict__ shift) {
    int o = threadIdx.x;
    float cnt = (float)(B_ * SP);
    float mu = bnsum[o] / cnt;
    float var = bnsq[o] / cnt - mu * mu;
    float sc = bn_g[o] * rsqrtf(var + 1e-5f);
    scale[o] = sc;
    shift[o] = bn_b[o] - mu * sc;
}

// ---------------- K8: BN apply + relu, in place on d_out
__global__ __launch_bounds__(256) void k8_apply(float* __restrict__ y,
        const float* __restrict__ scale, const float* __restrict__ shift) {
    int i = blockIdx.x * 256 + threadIdx.x;      // float4 index
    int o = (i >> 10) & 255;
    float4 v = ((float4*)y)[i];
    float sc = scale[o], sh = shift[o];
    v.x = fmaxf(fmaf(v.x, sc, sh), 0.f);
    v.y = fmaxf(fmaf(v.y, sc, sh), 0.f);
    v.z = fmaxf(fmaf(v.z, sc, sh), 0.f);
    v.w = fmaxf(fmaf(v.w, sc, sh), 0.f);
    ((float4*)y)[i] = v;
}

extern "C" void kernel_launch(void* const* d_in, const int* in_sizes, int n_in,
                              void* d_out, int out_size, void* d_ws, size_t ws_size,
                              hipStream_t stream) {
    const float* x    = (const float*)d_in[0];
    const float* s_in = (const float*)d_in[1];
    const float* up_w = (const float*)d_in[2];
    const float* up_b = (const float*)d_in[3];
    const float* wq   = (const float*)d_in[4];
    const float* wkl  = (const float*)d_in[5];
    const float* wkr  = (const float*)d_in[6];
    const float* c1_w = (const float*)d_in[7];
    const float* c1_b = (const float*)d_in[8];
    const float* bn_g = (const float*)d_in[9];
    const float* bn_b = (const float*)d_in[10];
    float* y = (float*)d_out;
    float* ws = (float*)d_ws;

    size_t off = 0;
    float* qbuf  = ws + off; off += (size_t)T_ * INC * DK;
    float* klbuf = ws + off; off += (size_t)T_ * INC * DK;
    float* krbuf = ws + off; off += (size_t)T_ * INC * DK;
    float* kvl   = ws + off; off += (size_t)T_ * DK * FD;
    float* kvr   = ws + off; off += (size_t)T_ * DK * FD;
    float* ksuml = ws + off; off += (size_t)T_ * DK;
    float* ksumr = ws + off; off += (size_t)T_ * DK;
    float* zl    = ws + off; off += (size_t)T_ * INC;
    float* zr    = ws + off; off += (size_t)T_ * INC;
    float* newbuf= ws + off; off += (size_t)T_ * INC * FD;
    float* bnsum = ws + off; off += OUTC;
    float* bnsq  = ws + off; off += OUTC;
    float* scale = ws + off; off += OUTC;
    float* shift = ws + off; off += OUTC;
    u16* P  = (u16*)(ws + off); off += ((size_t)B_ * 66 * 66 * 512 + 1) / 2;  // bf16 padded input
    u16* Wt = (u16*)(ws + off); off += ((size_t)9 * 256 * 512 + 1) / 2;       // bf16 weights

    hipMemsetAsync(bnsum, 0, 2 * OUTC * sizeof(float), stream);
    hipMemsetAsync(P, 0, (size_t)B_ * 66 * 66 * 512 * sizeof(u16), stream);

    dim3 thr(16, 16);
    kw_tr<<<dim3((256 * 512 * 9 + 255) / 256), dim3(256), 0, stream>>>(c1_w, Wt);
    k1_proj<<<dim3(2, 8, 42), thr, 0, stream>>>(x, wq, wkl, wkr, qbuf, klbuf, krbuf);
    k2_kv<<<dim3(16, 2, 28), thr, 0, stream>>>(x, klbuf, krbuf, kvl, kvr);
    k2b_ksum<<<dim3(T_), dim3(DK), 0, stream>>>(klbuf, krbuf, ksuml, ksumr);
    k2c_z<<<dim3(T_), dim3(INC), 0, stream>>>(qbuf, ksuml, ksumr, zl, zr);
    k3_out<<<dim3(16, 8, T_), thr, 0, stream>>>(x, qbuf, kvl, kvr, zl, zr, newbuf);
    k4_up<<<dim3(16, 16, B_), thr, 0, stream>>>(x, newbuf, up_w, up_b, s_in, P);
    k4b_sfill<<<dim3(64, B_), dim3(256), 0, stream>>>(s_in, P);
    k5_mfma<<<dim3(16, 4, B_), dim3(256), 0, stream>>>(P, Wt, c1_b, y);
    k6_bnred<<<dim3(B_, OUTC), dim3(256), 0, stream>>>(y, bnsum, bnsq);
    k7_bnfin<<<dim3(1), dim3(OUTC), 0, stream>>>(bnsum, bnsq, bn_g, bn_b, scale, shift);
    k8_apply<<<dim3((B_ * OUTC * SP / 4) / 256), dim3(256), 0, stream>>>(y, scale, shift);
}

// Round 3
// 708.878 us; speedup vs baseline: 4.9267x; 1.3560x over previous
//
#include <hip/hip_runtime.h>
#include <math.h>

#define B_ 16
#define INC 512
#define OUTC 256
#define FD 1024
#define DK 128
#define T_ 14
#define HO 64
#define WO 64
#define SP (HO*WO)
#define KCP 40   // padded channel stride in conv LDS slab

typedef unsigned short u16;
typedef __attribute__((ext_vector_type(8))) short shortx8;
typedef __attribute__((ext_vector_type(4))) float floatx4;

__device__ __forceinline__ float phi_f(float t) {
    return t > 0.0f ? t + 1.0f : expf(t);
}
__device__ __forceinline__ u16 f2bf(float f) {
    unsigned int u = __float_as_uint(f);
    unsigned int r = (u + 0x7fffu + ((u >> 16) & 1u)) >> 16;
    return (u16)r;
}
__device__ __forceinline__ float bf2f(u16 h) {
    return __uint_as_float(((unsigned int)h) << 16);
}

// ---------------- prep: xT[b][d][c] bf16 from x[b][c][d] fp32
__global__ __launch_bounds__(256) void kprep_x(const float* __restrict__ x, u16* __restrict__ xT) {
    __shared__ u16 T[64][65];
    int d0 = blockIdx.x * 64, c0 = blockIdx.y * 64, b = blockIdx.z;
    const float* src = x + (size_t)b * INC * FD;
    int tid = threadIdx.x, lr = tid >> 6, lc = tid & 63;
    #pragma unroll
    for (int i = 0; i < 16; ++i) {
        int c = lr + i * 4;
        T[lc][c] = f2bf(src[(size_t)(c0 + c) * FD + d0 + lc]);
    }
    __syncthreads();
    u16* dst = xT + (size_t)b * FD * INC;
    #pragma unroll
    for (int i = 0; i < 16; ++i) {
        int d = lr + i * 4;
        dst[(size_t)(d0 + d) * INC + c0 + lc] = T[d][lc];
    }
}

// ---------------- prep: generic transpose fp32[R][C] -> bf16[C][R]
__global__ __launch_bounds__(256) void ktr_w(const float* __restrict__ src, u16* __restrict__ dst,
                                             int R, int C) {
    __shared__ u16 T[64][65];
    int c0 = blockIdx.x * 64, r0 = blockIdx.y * 64;
    int tid = threadIdx.x, lr = tid >> 6, lc = tid & 63;
    #pragma unroll
    for (int i = 0; i < 16; ++i) {
        int r = lr + i * 4;
        T[lc][r] = f2bf(src[(size_t)(r0 + r) * C + c0 + lc]);
    }
    __syncthreads();
    #pragma unroll
    for (int i = 0; i < 16; ++i) {
        int c = lr + i * 4;
        dst[(size_t)(c0 + c) * R + r0 + lc] = T[c][lc];
    }
}

// ---------------- prep: conv weights to Wt[tap][o][c] bf16
__global__ void kw_tr(const float* __restrict__ c1_w, u16* __restrict__ Wt) {
    int i = blockIdx.x * 256 + threadIdx.x;
    if (i >= 256 * 512 * 9) return;
    int tap = i % 9; int t2 = i / 9;
    int c = t2 % 512; int o = t2 / 512;
    Wt[((size_t)tap * 256 + o) * 512 + c] = f2bf(c1_w[i]);
}

// ---------------- K1: Q/KL/KR = phi(X @ W) via MFMA. M=512,N=128,K=1024.
// which==0 -> Q row-major [n][dk]; which 1/2 -> KLt/KRt transposed [dk][n].
__global__ __launch_bounds__(256) void k1_proj(const float* __restrict__ x,
        const u16* __restrict__ wqT, const u16* __restrict__ wklT, const u16* __restrict__ wkrT,
        u16* __restrict__ qb, u16* __restrict__ klt, u16* __restrict__ krt) {
    __shared__ u16 smem[8704];               // staging 7680; transpose 64*136=8704
    u16* As = smem;                          // 128 x 40
    u16* Bs = smem + 5120;                   // 64 x 40
    int z = blockIdx.z, t = z / 3, which = z - t * 3;
    int src = (which == 0) ? t + 1 : (which == 1 ? t : t + 2);
    const float* Af = x + (size_t)src * INC * FD;
    const u16* Bw = (which == 0) ? wqT : (which == 1 ? wklT : wkrT);
    int n0 = blockIdx.x * 64, m0 = blockIdx.y * 128;
    int tid = threadIdx.x, w = tid >> 6, lane = tid & 63, l15 = lane & 15, quad = lane >> 4;
    int sm = tid >> 2, sq = (tid & 3) * 8;
    floatx4 acc[2][4];
    #pragma unroll
    for (int i = 0; i < 2; ++i)
        #pragma unroll
        for (int j = 0; j < 4; ++j) acc[i][j] = (floatx4){0.f,0.f,0.f,0.f};

    for (int k0 = 0; k0 < FD; k0 += 32) {
        float4 v0 = *(const float4*)&Af[(size_t)(m0 + sm) * FD + k0 + sq];
        float4 v1 = *(const float4*)&Af[(size_t)(m0 + sm) * FD + k0 + sq + 4];
        float4 v2 = *(const float4*)&Af[(size_t)(m0 + 64 + sm) * FD + k0 + sq];
        float4 v3 = *(const float4*)&Af[(size_t)(m0 + 64 + sm) * FD + k0 + sq + 4];
        union { u16 h[8]; uint4 v; } p0, p1;
        p0.h[0]=f2bf(v0.x); p0.h[1]=f2bf(v0.y); p0.h[2]=f2bf(v0.z); p0.h[3]=f2bf(v0.w);
        p0.h[4]=f2bf(v1.x); p0.h[5]=f2bf(v1.y); p0.h[6]=f2bf(v1.z); p0.h[7]=f2bf(v1.w);
        p1.h[0]=f2bf(v2.x); p1.h[1]=f2bf(v2.y); p1.h[2]=f2bf(v2.z); p1.h[3]=f2bf(v2.w);
        p1.h[4]=f2bf(v3.x); p1.h[5]=f2bf(v3.y); p1.h[6]=f2bf(v3.z); p1.h[7]=f2bf(v3.w);
        *(uint4*)&As[sm * 40 + sq] = p0.v;
        *(uint4*)&As[(64 + sm) * 40 + sq] = p1.v;
        *(uint4*)&Bs[sm * 40 + sq] = *(const uint4*)&Bw[(size_t)(n0 + sm) * FD + k0 + sq];
        __syncthreads();
        shortx8 bfr[4];
        #pragma unroll
        for (int nt = 0; nt < 4; ++nt)
            bfr[nt] = *(const shortx8*)&Bs[(nt * 16 + l15) * 40 + quad * 8];
        #pragma unroll
        for (int mt = 0; mt < 2; ++mt) {
            shortx8 af = *(const shortx8*)&As[(w * 32 + mt * 16 + l15) * 40 + quad * 8];
            #pragma unroll
            for (int nt = 0; nt < 4; ++nt)
                acc[mt][nt] = __builtin_amdgcn_mfma_f32_16x16x32_bf16(af, bfr[nt], acc[mt][nt], 0, 0, 0);
        }
        __syncthreads();
    }
    if (which == 0) {
        u16* outp = qb + (size_t)t * INC * DK;
        #pragma unroll
        for (int mt = 0; mt < 2; ++mt)
            #pragma unroll
            for (int nt = 0; nt < 4; ++nt)
                #pragma unroll
                for (int r = 0; r < 4; ++r) {
                    int m_out = m0 + w * 32 + mt * 16 + quad * 4 + r;
                    int n_out = n0 + nt * 16 + l15;
                    outp[(size_t)m_out * DK + n_out] = f2bf(phi_f(acc[mt][nt][r]));
                }
    } else {
        u16* outp = ((which == 1) ? klt : krt) + (size_t)t * DK * INC;
        #pragma unroll
        for (int mt = 0; mt < 2; ++mt)
            #pragma unroll
            for (int nt = 0; nt < 4; ++nt)
                #pragma unroll
                for (int r = 0; r < 4; ++r) {
                    int mloc = w * 32 + mt * 16 + quad * 4 + r;   // n local (0..127)
                    int nloc = nt * 16 + l15;                     // dk local (0..63)
                    smem[nloc * 136 + mloc] = f2bf(phi_f(acc[mt][nt][r]));
                }
        __syncthreads();
        int dkl = tid >> 2, seg = tid & 3;
        const uint4* sp = (const uint4*)&smem[dkl * 136 + seg * 32];
        uint4* dp = (uint4*)&outp[(size_t)(n0 + dkl) * INC + m0 + seg * 32];
        dp[0] = sp[0]; dp[1] = sp[1]; dp[2] = sp[2]; dp[3] = sp[3];
    }
}

// ---------------- K2b: ksum[dk] = sum_n KL[n][dk] (row sums of KLt)
__global__ void k2b_ksum(const u16* __restrict__ klt, const u16* __restrict__ krt,
                         float* __restrict__ ksuml, float* __restrict__ ksumr) {
    int t = blockIdx.x; int dk = threadIdx.x;
    const u16* pl = klt + ((size_t)t * DK + dk) * INC;
    const u16* pr = krt + ((size_t)t * DK + dk) * INC;
    float s1 = 0.f, s2 = 0.f;
    for (int n = 0; n < INC; ++n) { s1 += bf2f(pl[n]); s2 += bf2f(pr[n]); }
    ksuml[t * DK + dk] = s1; ksumr[t * DK + dk] = s2;
}

// ---------------- K2c: z[n] = q[n,:].ksum + 1e-6
__global__ void k2c_z(const u16* __restrict__ qb, const float* __restrict__ ksuml,
                      const float* __restrict__ ksumr, float* __restrict__ zl, float* __restrict__ zr) {
    int t = blockIdx.x; int n = threadIdx.x;
    const u16* q = qb + ((size_t)t * INC + n) * DK;
    const float* sl = ksuml + t * DK;
    const float* sr = ksumr + t * DK;
    float a = 0.f, b = 0.f;
    for (int k = 0; k < DK; ++k) { float qv = bf2f(q[k]); a = fmaf(qv, sl[k], a); b = fmaf(qv, sr[k], b); }
    zl[t * INC + n] = a + 1e-6f;
    zr[t * INC + n] = b + 1e-6f;
}

// ---------------- K2: KVt[d][dk] = xT @ KLt-frag. M=1024,N=128,K=512.
__global__ __launch_bounds__(256) void k2_kv(const u16* __restrict__ xT,
        const u16* __restrict__ klt, const u16* __restrict__ krt,
        u16* __restrict__ kvlT, u16* __restrict__ kvrT) {
    __shared__ u16 As[128 * 40];
    __shared__ u16 Bs[64 * 40];
    int z = blockIdx.z, t = z >> 1, side = z & 1;
    const u16* A = xT + (size_t)(side ? t + 2 : t) * FD * INC;
    const u16* Bw = (side ? krt : klt) + (size_t)t * DK * INC;
    u16* outp = (side ? kvrT : kvlT) + (size_t)t * FD * DK;
    int n0 = blockIdx.x * 64, m0 = blockIdx.y * 128;
    int tid = threadIdx.x, w = tid >> 6, lane = tid & 63, l15 = lane & 15, quad = lane >> 4;
    int sm = tid >> 2, sq = (tid & 3) * 8;
    floatx4 acc[2][4];
    #pragma unroll
    for (int i = 0; i < 2; ++i)
        #pragma unroll
        for (int j = 0; j < 4; ++j) acc[i][j] = (floatx4){0.f,0.f,0.f,0.f};
    for (int k0 = 0; k0 < INC; k0 += 32) {
        *(uint4*)&As[sm * 40 + sq] = *(const uint4*)&A[(size_t)(m0 + sm) * INC + k0 + sq];
        *(uint4*)&As[(64 + sm) * 40 + sq] = *(const uint4*)&A[(size_t)(m0 + 64 + sm) * INC + k0 + sq];
        *(uint4*)&Bs[sm * 40 + sq] = *(const uint4*)&Bw[(size_t)(n0 + sm) * INC + k0 + sq];
        __syncthreads();
        shortx8 bfr[4];
        #pragma unroll
        for (int nt = 0; nt < 4; ++nt)
            bfr[nt] = *(const shortx8*)&Bs[(nt * 16 + l15) * 40 + quad * 8];
        #pragma unroll
        for (int mt = 0; mt < 2; ++mt) {
            shortx8 af = *(const shortx8*)&As[(w * 32 + mt * 16 + l15) * 40 + quad * 8];
            #pragma unroll
            for (int nt = 0; nt < 4; ++nt)
                acc[mt][nt] = __builtin_amdgcn_mfma_f32_16x16x32_bf16(af, bfr[nt], acc[mt][nt], 0, 0, 0);
        }
        __syncthreads();
    }
    #pragma unroll
    for (int mt = 0; mt < 2; ++mt)
        #pragma unroll
        for (int nt = 0; nt < 4; ++nt)
            #pragma unroll
            for (int r = 0; r < 4; ++r) {
                int m_out = m0 + w * 32 + mt * 16 + quad * 4 + r;
                int n_out = n0 + nt * 16 + l15;
                outp[(size_t)m_out * DK + n_out] = f2bf(acc[mt][nt][r]);
            }
}

// ---------------- K3: newT[d][n] = KVtL@Q^T/zl + KVtR@Q^T/zr + xT. M=1024,N=512,K=128.
__global__ __launch_bounds__(256) void k3_out(const u16* __restrict__ xT,
        const u16* __restrict__ qb, const u16* __restrict__ kvlT, const u16* __restrict__ kvrT,
        const float* __restrict__ zl, const float* __restrict__ zr, u16* __restrict__ newT) {
    __shared__ u16 As1[128 * 40];
    __shared__ u16 As2[128 * 40];
    __shared__ u16 Bs[64 * 40];
    int t = blockIdx.z;
    const u16* A1 = kvlT + (size_t)t * FD * DK;
    const u16* A2 = kvrT + (size_t)t * FD * DK;
    const u16* Bq = qb + (size_t)t * INC * DK;
    int n0 = blockIdx.x * 64, m0 = blockIdx.y * 128;
    int tid = threadIdx.x, w = tid >> 6, lane = tid & 63, l15 = lane & 15, quad = lane >> 4;
    int sm = tid >> 2, sq = (tid & 3) * 8;
    floatx4 accl[2][4], accr[2][4];
    #pragma unroll
    for (int i = 0; i < 2; ++i)
        #pragma unroll
        for (int j = 0; j < 4; ++j) {
            accl[i][j] = (floatx4){0.f,0.f,0.f,0.f};
            accr[i][j] = (floatx4){0.f,0.f,0.f,0.f};
        }
    for (int k0 = 0; k0 < DK; k0 += 32) {
        *(uint4*)&As1[sm * 40 + sq] = *(const uint4*)&A1[(size_t)(m0 + sm) * DK + k0 + sq];
        *(uint4*)&As1[(64 + sm) * 40 + sq] = *(const uint4*)&A1[(size_t)(m0 + 64 + sm) * DK + k0 + sq];
        *(uint4*)&As2[sm * 40 + sq] = *(const uint4*)&A2[(size_t)(m0 + sm) * DK + k0 + sq];
        *(uint4*)&As2[(64 + sm) * 40 + sq] = *(const uint4*)&A2[(size_t)(m0 + 64 + sm) * DK + k0 + sq];
        *(uint4*)&Bs[sm * 40 + sq] = *(const uint4*)&Bq[(size_t)(n0 + sm) * DK + k0 + sq];
        __syncthreads();
        shortx8 bfr[4];
        #pragma unroll
        for (int nt = 0; nt < 4; ++nt)
            bfr[nt] = *(const shortx8*)&Bs[(nt * 16 + l15) * 40 + quad * 8];
        #pragma unroll
        for (int mt = 0; mt < 2; ++mt) {
            shortx8 afl = *(const shortx8*)&As1[(w * 32 + mt * 16 + l15) * 40 + quad * 8];
            shortx8 afr = *(const shortx8*)&As2[(w * 32 + mt * 16 + l15) * 40 + quad * 8];
            #pragma unroll
            for (int nt = 0; nt < 4; ++nt) {
                accl[mt][nt] = __builtin_amdgcn_mfma_f32_16x16x32_bf16(afl, bfr[nt], accl[mt][nt], 0, 0, 0);
                accr[mt][nt] = __builtin_amdgcn_mfma_f32_16x16x32_bf16(afr, bfr[nt], accr[mt][nt], 0, 0, 0);
            }
        }
        __syncthreads();
    }
    float il[4], ir[4];
    #pragma unroll
    for (int nt = 0; nt < 4; ++nt) {
        int n_out = n0 + nt * 16 + l15;
        il[nt] = 1.0f / zl[t * INC + n_out];
        ir[nt] = 1.0f / zr[t * INC + n_out];
    }
    const u16* xc = xT + (size_t)(t + 1) * FD * INC;
    u16* outp = newT + (size_t)t * FD * INC;
    #pragma unroll
    for (int mt = 0; mt < 2; ++mt)
        #pragma unroll
        for (int nt = 0; nt < 4; ++nt)
            #pragma unroll
            for (int r = 0; r < 4; ++r) {
                int m_out = m0 + w * 32 + mt * 16 + quad * 4 + r;
                int n_out = n0 + nt * 16 + l15;
                float xv = bf2f(xc[(size_t)m_out * INC + n_out]);
                float v = xv + accl[mt][nt][r] * il[nt] + accr[mt][nt][r] * ir[nt];
                outp[(size_t)m_out * INC + n_out] = f2bf(v);
            }
}

// ---------------- K4: upT[px][m] = newT @ upwT + gate, writes P channels 0..255.
__global__ __launch_bounds__(256) void k4_up(const u16* __restrict__ xT,
        const u16* __restrict__ newT, const u16* __restrict__ upwT,
        const float* __restrict__ up_b, u16* __restrict__ P) {
    __shared__ u16 As[128 * 40];
    __shared__ u16 Bs[64 * 40];
    int b = blockIdx.z;
    const u16* A = (b == 0) ? xT
                 : (b == B_ - 1) ? (xT + (size_t)(B_ - 1) * FD * INC)
                 : (newT + (size_t)(b - 1) * FD * INC);
    int n0 = blockIdx.x * 64, m0 = blockIdx.y * 128;
    int tid = threadIdx.x, w = tid >> 6, lane = tid & 63, l15 = lane & 15, quad = lane >> 4;
    int sm = tid >> 2, sq = (tid & 3) * 8;
    floatx4 acc[2][4];
    #pragma unroll
    for (int i = 0; i < 2; ++i)
        #pragma unroll
        for (int j = 0; j < 4; ++j) acc[i][j] = (floatx4){0.f,0.f,0.f,0.f};
    for (int k0 = 0; k0 < INC; k0 += 32) {
        *(uint4*)&As[sm * 40 + sq] = *(const uint4*)&A[(size_t)(m0 + sm) * INC + k0 + sq];
        *(uint4*)&As[(64 + sm) * 40 + sq] = *(const uint4*)&A[(size_t)(m0 + 64 + sm) * INC + k0 + sq];
        *(uint4*)&Bs[sm * 40 + sq] = *(const uint4*)&upwT[(size_t)(n0 + sm) * INC + k0 + sq];
        __syncthreads();
        shortx8 bfr[4];
        #pragma unroll
        for (int nt = 0; nt < 4; ++nt)
            bfr[nt] = *(const shortx8*)&Bs[(nt * 16 + l15) * 40 + quad * 8];
        #pragma unroll
        for (int mt = 0; mt < 2; ++mt) {
            shortx8 af = *(const shortx8*)&As[(w * 32 + mt * 16 + l15) * 40 + quad * 8];
            #pragma unroll
            for (int nt = 0; nt < 4; ++nt)
                acc[mt][nt] = __builtin_amdgcn_mfma_f32_16x16x32_bf16(af, bfr[nt], acc[mt][nt], 0, 0, 0);
        }
        __syncthreads();
    }
    #pragma unroll
    for (int mt = 0; mt < 2; ++mt)
        #pragma unroll
        for (int nt = 0; nt < 4; ++nt) {
            int mm = n0 + nt * 16 + l15;
            int o = mm >> 2, aa = (mm >> 1) & 1, cb = mm & 1;
            float bias = up_b[o];
            #pragma unroll
            for (int r = 0; r < 4; ++r) {
                int px = m0 + w * 32 + mt * 16 + quad * 4 + r;
                int ii = px >> 5, jj = px & 31;
                int p = 2 * ii + aa, q = 2 * jj + cb;
                size_t pos = ((size_t)(b * 66 + 1 + p) * 66 + 1 + q) * 512;
                float sv = bf2f(P[pos + 256 + o]);
                float up = acc[mt][nt][r] + bias;
                float rr = fmaxf(up + sv, 0.0f);
                P[pos + o] = f2bf(1.0f / (1.0f + expf(-rr)));
            }
        }
}

// ---------------- K4b: skip s -> bf16 into padded P (channels 256..511)
__global__ __launch_bounds__(256) void k4b_sfill(const float* __restrict__ s_in,
                                                 u16* __restrict__ P) {
    __shared__ u16 T[64 * 264];
    int p = blockIdx.x;
    int b = blockIdx.y;
    int tid = threadIdx.x;
    int qcol = tid & 63;
    int ob = tid >> 6;
    for (int o = ob; o < 256; o += 4) {
        float v = s_in[((size_t)(b * OUTC + o) * HO + p) * WO + qcol];
        T[qcol * 264 + o] = f2bf(v);
    }
    __syncthreads();
    int q2 = tid >> 2;
    int sg = tid & 3;
    size_t base = ((size_t)(b * 66 + 1 + p) * 66 + 1 + q2) * 512 + 256;
    #pragma unroll
    for (int it = 0; it < 8; ++it) {
        int seg = sg + it * 4;
        uint4 v = *(const uint4*)&T[q2 * 264 + seg * 8];
        *(uint4*)(P + base + seg * 8) = v;
    }
}

// ---------------- K5: conv3x3 as MFMA implicit GEMM (unchanged from round 2)
__global__ __launch_bounds__(256) void k5_mfma(const u16* __restrict__ P,
        const u16* __restrict__ Wt, const float* __restrict__ c1_b,
        float* __restrict__ y) {
    __shared__ u16 Xs[6 * 66 * KCP];
    int rb = blockIdx.x;
    int o0 = blockIdx.y * 64;
    int b  = blockIdx.z;
    int tid = threadIdx.x;
    int w = tid >> 6, lane = tid & 63;
    int l15 = lane & 15, quad = lane >> 4;

    floatx4 acc[4][4];
    #pragma unroll
    for (int i = 0; i < 4; ++i)
        #pragma unroll
        for (int j = 0; j < 4; ++j)
            acc[i][j] = (floatx4){0.f, 0.f, 0.f, 0.f};

    size_t Pbase = ((size_t)b * 66 + (size_t)rb * 4) * 66 * 512;

    for (int ch = 0; ch < 16; ++ch) {
        int c0 = ch * 32;
        __syncthreads();
        for (int s = tid; s < 1584; s += 256) {
            int r = s / 264; int rem = s - r * 264;
            int col = rem >> 2; int cs = rem & 3;
            uint4 v = *(const uint4*)(P + Pbase + ((size_t)r * 66 + col) * 512 + c0 + cs * 8);
            *(uint4*)&Xs[(r * 66 + col) * KCP + cs * 8] = v;
        }
        __syncthreads();
        #pragma unroll
        for (int dy = 0; dy < 3; ++dy) {
            #pragma unroll
            for (int dx = 0; dx < 3; ++dx) {
                int tap = dy * 3 + dx;
                shortx8 wf[4];
                #pragma unroll
                for (int nt = 0; nt < 4; ++nt)
                    wf[nt] = *(const shortx8*)(Wt +
                        ((size_t)(tap * 256 + o0 + nt * 16 + l15)) * 512 + c0 + quad * 8);
                #pragma unroll
                for (int mt = 0; mt < 4; ++mt) {
                    shortx8 af = *(const shortx8*)&Xs[((w + dy) * 66 + mt * 16 + l15 + dx) * KCP + quad * 8];
                    #pragma unroll
                    for (int nt = 0; nt < 4; ++nt)
                        acc[mt][nt] = __builtin_amdgcn_mfma_f32_16x16x32_bf16(
                            af, wf[nt], acc[mt][nt], 0, 0, 0);
                }
            }
        }
    }
    int row = rb * 4 + w;
    float bias[4];
    #pragma unroll
    for (int nt = 0; nt < 4; ++nt) bias[nt] = c1_b[o0 + nt * 16 + l15];
    #pragma unroll
    for (int mt = 0; mt < 4; ++mt) {
        #pragma unroll
        for (int nt = 0; nt < 4; ++nt) {
            int o = o0 + nt * 16 + l15;
            size_t ybase = (size_t)(b * OUTC + o) * SP + row * 64;
            #pragma unroll
            for (int r = 0; r < 4; ++r) {
                int col = mt * 16 + quad * 4 + r;
                y[ybase + col] = acc[mt][nt][r] + bias[nt];
            }
        }
    }
}

// ---------------- K6: BN stats reduce
__global__ __launch_bounds__(256) void k6_bnred(const float* __restrict__ y,
        float* __restrict__ bnsum, float* __restrict__ bnsq) {
    int b = blockIdx.x, o = blockIdx.y;
    const float* p = y + ((size_t)b * OUTC + o) * SP;
    float s1 = 0.f, s2 = 0.f;
    for (int i = threadIdx.x; i < SP; i += 256) { float v = p[i]; s1 += v; s2 = fmaf(v, v, s2); }
    #pragma unroll
    for (int off = 32; off > 0; off >>= 1) {
        s1 += __shfl_down(s1, off, 64);
        s2 += __shfl_down(s2, off, 64);
    }
    __shared__ float r1[4], r2[4];
    int wid = threadIdx.x >> 6, lane = threadIdx.x & 63;
    if (lane == 0) { r1[wid] = s1; r2[wid] = s2; }
    __syncthreads();
    if (threadIdx.x == 0) {
        atomicAdd(&bnsum[o], r1[0] + r1[1] + r1[2] + r1[3]);
        atomicAdd(&bnsq[o],  r2[0] + r2[1] + r2[2] + r2[3]);
    }
}

// ---------------- K7: BN finalize
__global__ void k7_bnfin(const float* __restrict__ bnsum, const float* __restrict__ bnsq,
                         const float* __restrict__ bn_g, const float* __restrict__ bn_b,
                         float* __restrict__ scale, float* __restrict__ shift) {
    int o = threadIdx.x;
    float cnt = (float)(B_ * SP);
    float mu = bnsum[o] / cnt;
    float var = bnsq[o] / cnt - mu * mu;
    float sc = bn_g[o] * rsqrtf(var + 1e-5f);
    scale[o] = sc;
    shift[o] = bn_b[o] - mu * sc;
}

// ---------------- K8: BN apply + relu
__global__ __launch_bounds__(256) void k8_apply(float* __restrict__ y,
        const float* __restrict__ scale, const float* __restrict__ shift) {
    int i = blockIdx.x * 256 + threadIdx.x;
    int o = (i >> 10) & 255;
    float4 v = ((float4*)y)[i];
    float sc = scale[o], sh = shift[o];
    v.x = fmaxf(fmaf(v.x, sc, sh), 0.f);
    v.y = fmaxf(fmaf(v.y, sc, sh), 0.f);
    v.z = fmaxf(fmaf(v.z, sc, sh), 0.f);
    v.w = fmaxf(fmaf(v.w, sc, sh), 0.f);
    ((float4*)y)[i] = v;
}

extern "C" void kernel_launch(void* const* d_in, const int* in_sizes, int n_in,
                              void* d_out, int out_size, void* d_ws, size_t ws_size,
                              hipStream_t stream) {
    const float* x    = (const float*)d_in[0];
    const float* s_in = (const float*)d_in[1];
    const float* up_w = (const float*)d_in[2];
    const float* up_b = (const float*)d_in[3];
    const float* wq   = (const float*)d_in[4];
    const float* wkl  = (const float*)d_in[5];
    const float* wkr  = (const float*)d_in[6];
    const float* c1_w = (const float*)d_in[7];
    const float* c1_b = (const float*)d_in[8];
    const float* bn_g = (const float*)d_in[9];
    const float* bn_b = (const float*)d_in[10];
    float* y = (float*)d_out;
    float* ws = (float*)d_ws;

    size_t off = 0;
    float* ksuml = ws + off; off += (size_t)T_ * DK;
    float* ksumr = ws + off; off += (size_t)T_ * DK;
    float* zl    = ws + off; off += (size_t)T_ * INC;
    float* zr    = ws + off; off += (size_t)T_ * INC;
    float* bnsum = ws + off; off += OUTC;
    float* bnsq  = ws + off; off += OUTC;
    float* scale = ws + off; off += OUTC;
    float* shift = ws + off; off += OUTC;

    u16* ub = (u16*)(ws + off);
    size_t uo = 0;
    u16* qb   = ub + uo; uo += (size_t)T_ * INC * DK;
    u16* klt  = ub + uo; uo += (size_t)T_ * DK * INC;
    u16* krt  = ub + uo; uo += (size_t)T_ * DK * INC;
    u16* kvlT = ub + uo; uo += (size_t)T_ * FD * DK;
    u16* kvrT = ub + uo; uo += (size_t)T_ * FD * DK;
    u16* newT = ub + uo; uo += (size_t)T_ * FD * INC;
    u16* xT   = ub + uo; uo += (size_t)B_ * FD * INC;
    u16* wqT  = ub + uo; uo += (size_t)DK * FD;
    u16* wklT = ub + uo; uo += (size_t)DK * FD;
    u16* wkrT = ub + uo; uo += (size_t)DK * FD;
    u16* upwT = ub + uo; uo += (size_t)FD * INC;
    u16* Wt   = ub + uo; uo += (size_t)9 * OUTC * 2 * INC;   // 9*256*512
    u16* P    = ub + uo; uo += (size_t)B_ * 66 * 66 * 512;

    hipMemsetAsync(bnsum, 0, 2 * OUTC * sizeof(float), stream);
    hipMemsetAsync(P, 0, (size_t)B_ * 66 * 66 * 512 * sizeof(u16), stream);

    kprep_x<<<dim3(16, 8, B_), dim3(256), 0, stream>>>(x, xT);
    ktr_w<<<dim3(2, 16), dim3(256), 0, stream>>>(wq, wqT, FD, DK);
    ktr_w<<<dim3(2, 16), dim3(256), 0, stream>>>(wkl, wklT, FD, DK);
    ktr_w<<<dim3(2, 16), dim3(256), 0, stream>>>(wkr, wkrT, FD, DK);
    ktr_w<<<dim3(16, 8), dim3(256), 0, stream>>>(up_w, upwT, INC, FD);
    kw_tr<<<dim3((256 * 512 * 9 + 255) / 256), dim3(256), 0, stream>>>(c1_w, Wt);

    k1_proj<<<dim3(2, 4, 42), dim3(256), 0, stream>>>(x, wqT, wklT, wkrT, qb, klt, krt);
    k2b_ksum<<<dim3(T_), dim3(DK), 0, stream>>>(klt, krt, ksuml, ksumr);
    k2c_z<<<dim3(T_), dim3(INC), 0, stream>>>(qb, ksuml, ksumr, zl, zr);
    k2_kv<<<dim3(2, 8, 28), dim3(256), 0, stream>>>(xT, klt, krt, kvlT, kvrT);
    k3_out<<<dim3(8, 8, T_), dim3(256), 0, stream>>>(xT, qb, kvlT, kvrT, zl, zr, newT);
    k4b_sfill<<<dim3(64, B_), dim3(256), 0, stream>>>(s_in, P);
    k4_up<<<dim3(16, 8, B_), dim3(256), 0, stream>>>(xT, newT, upwT, up_b, P);
    k5_mfma<<<dim3(16, 4, B_), dim3(256), 0, stream>>>(P, Wt, c1_b, y);
    k6_bnred<<<dim3(B_, OUTC), dim3(256), 0, stream>>>(y, bnsum, bnsq);
    k7_bnfin<<<dim3(1), dim3(OUTC), 0, stream>>>(bnsum, bnsq, bn_g, bn_b, scale, shift);
    k8_apply<<<dim3((B_ * OUTC * SP / 4) / 256), dim3(256), 0, stream>>>(y, scale, shift);
}

// Round 4
// 687.565 us; speedup vs baseline: 5.0794x; 1.0310x over previous
//
#include <hip/hip_runtime.h>
#include <math.h>

#define B_ 16
#define INC 512
#define OUTC 256
#define FD 1024
#define DK 128
#define T_ 14
#define HO 64
#define WO 64
#define SP (HO*WO)
#define KC5 32   // conv LDS slab channel stride (unpadded: required for global_load_lds linear dst)

typedef unsigned short u16;
typedef __attribute__((ext_vector_type(8))) short shortx8;
typedef __attribute__((ext_vector_type(4))) float floatx4;

__device__ __forceinline__ float phi_f(float t) {
    return t > 0.0f ? t + 1.0f : expf(t);
}
__device__ __forceinline__ u16 f2bf(float f) {
    unsigned int u = __float_as_uint(f);
    unsigned int r = (u + 0x7fffu + ((u >> 16) & 1u)) >> 16;
    return (u16)r;
}
__device__ __forceinline__ float bf2f(u16 h) {
    return __uint_as_float(((unsigned int)h) << 16);
}

// ---------------- prep: xT[b][d][c] bf16 from x[b][c][d] fp32
__global__ __launch_bounds__(256) void kprep_x(const float* __restrict__ x, u16* __restrict__ xT) {
    __shared__ u16 T[64][65];
    int d0 = blockIdx.x * 64, c0 = blockIdx.y * 64, b = blockIdx.z;
    const float* src = x + (size_t)b * INC * FD;
    int tid = threadIdx.x, lr = tid >> 6, lc = tid & 63;
    #pragma unroll
    for (int i = 0; i < 16; ++i) {
        int c = lr + i * 4;
        T[lc][c] = f2bf(src[(size_t)(c0 + c) * FD + d0 + lc]);
    }
    __syncthreads();
    u16* dst = xT + (size_t)b * FD * INC;
    #pragma unroll
    for (int i = 0; i < 16; ++i) {
        int d = lr + i * 4;
        dst[(size_t)(d0 + d) * INC + c0 + lc] = T[d][lc];
    }
}

// ---------------- prep: generic transpose fp32[R][C] -> bf16[C][R]
__global__ __launch_bounds__(256) void ktr_w(const float* __restrict__ src, u16* __restrict__ dst,
                                             int R, int C) {
    __shared__ u16 T[64][65];
    int c0 = blockIdx.x * 64, r0 = blockIdx.y * 64;
    int tid = threadIdx.x, lr = tid >> 6, lc = tid & 63;
    #pragma unroll
    for (int i = 0; i < 16; ++i) {
        int r = lr + i * 4;
        T[lc][r] = f2bf(src[(size_t)(r0 + r) * C + c0 + lc]);
    }
    __syncthreads();
    #pragma unroll
    for (int i = 0; i < 16; ++i) {
        int c = lr + i * 4;
        dst[(size_t)(c0 + c) * R + r0 + lc] = T[c][lc];
    }
}

// ---------------- prep: conv weights to Wt[tap][o][c] bf16
__global__ void kw_tr(const float* __restrict__ c1_w, u16* __restrict__ Wt) {
    int i = blockIdx.x * 256 + threadIdx.x;
    if (i >= 256 * 512 * 9) return;
    int tap = i % 9; int t2 = i / 9;
    int c = t2 % 512; int o = t2 / 512;
    Wt[((size_t)tap * 256 + o) * 512 + c] = f2bf(c1_w[i]);
}

// ---------------- prep: zero only the border ring of padded P (interior fully overwritten)
__global__ __launch_bounds__(256) void kborder(u16* __restrict__ P) {
    int b = blockIdx.y;
    int cbase = blockIdx.x * 20;           // 13 * 20 = 260 border cells
    uint4 z = {0, 0, 0, 0};
    for (int i = threadIdx.x; i < 20 * 64; i += 256) {
        int c = cbase + (i >> 6);
        int sub = i & 63;
        int row, col;
        if (c < 66)       { row = 0;       col = c; }
        else if (c < 132) { row = 65;      col = c - 66; }
        else if (c < 196) { row = c - 131; col = 0; }
        else              { row = c - 195; col = 65; }
        *(uint4*)(P + ((size_t)(b * 66 + row) * 66 + col) * 512 + sub * 8) = z;
    }
}

// ---------------- K1: Q/KL/KR = phi(X @ W) via MFMA. M=512,N=128,K=1024.
__global__ __launch_bounds__(256) void k1_proj(const float* __restrict__ x,
        const u16* __restrict__ wqT, const u16* __restrict__ wklT, const u16* __restrict__ wkrT,
        u16* __restrict__ qb, u16* __restrict__ klt, u16* __restrict__ krt) {
    __shared__ u16 smem[8704];               // staging 7680; transpose 64*136=8704
    u16* As = smem;                          // 128 x 40
    u16* Bs = smem + 5120;                   // 64 x 40
    int z = blockIdx.z, t = z / 3, which = z - t * 3;
    int src = (which == 0) ? t + 1 : (which == 1 ? t : t + 2);
    const float* Af = x + (size_t)src * INC * FD;
    const u16* Bw = (which == 0) ? wqT : (which == 1 ? wklT : wkrT);
    int n0 = blockIdx.x * 64, m0 = blockIdx.y * 128;
    int tid = threadIdx.x, w = tid >> 6, lane = tid & 63, l15 = lane & 15, quad = lane >> 4;
    int sm = tid >> 2, sq = (tid & 3) * 8;
    floatx4 acc[2][4];
    #pragma unroll
    for (int i = 0; i < 2; ++i)
        #pragma unroll
        for (int j = 0; j < 4; ++j) acc[i][j] = (floatx4){0.f,0.f,0.f,0.f};

    for (int k0 = 0; k0 < FD; k0 += 32) {
        float4 v0 = *(const float4*)&Af[(size_t)(m0 + sm) * FD + k0 + sq];
        float4 v1 = *(const float4*)&Af[(size_t)(m0 + sm) * FD + k0 + sq + 4];
        float4 v2 = *(const float4*)&Af[(size_t)(m0 + 64 + sm) * FD + k0 + sq];
        float4 v3 = *(const float4*)&Af[(size_t)(m0 + 64 + sm) * FD + k0 + sq + 4];
        union { u16 h[8]; uint4 v; } p0, p1;
        p0.h[0]=f2bf(v0.x); p0.h[1]=f2bf(v0.y); p0.h[2]=f2bf(v0.z); p0.h[3]=f2bf(v0.w);
        p0.h[4]=f2bf(v1.x); p0.h[5]=f2bf(v1.y); p0.h[6]=f2bf(v1.z); p0.h[7]=f2bf(v1.w);
        p1.h[0]=f2bf(v2.x); p1.h[1]=f2bf(v2.y); p1.h[2]=f2bf(v2.z); p1.h[3]=f2bf(v2.w);
        p1.h[4]=f2bf(v3.x); p1.h[5]=f2bf(v3.y); p1.h[6]=f2bf(v3.z); p1.h[7]=f2bf(v3.w);
        *(uint4*)&As[sm * 40 + sq] = p0.v;
        *(uint4*)&As[(64 + sm) * 40 + sq] = p1.v;
        *(uint4*)&Bs[sm * 40 + sq] = *(const uint4*)&Bw[(size_t)(n0 + sm) * FD + k0 + sq];
        __syncthreads();
        shortx8 bfr[4];
        #pragma unroll
        for (int nt = 0; nt < 4; ++nt)
            bfr[nt] = *(const shortx8*)&Bs[(nt * 16 + l15) * 40 + quad * 8];
        #pragma unroll
        for (int mt = 0; mt < 2; ++mt) {
            shortx8 af = *(const shortx8*)&As[(w * 32 + mt * 16 + l15) * 40 + quad * 8];
            #pragma unroll
            for (int nt = 0; nt < 4; ++nt)
                acc[mt][nt] = __builtin_amdgcn_mfma_f32_16x16x32_bf16(af, bfr[nt], acc[mt][nt], 0, 0, 0);
        }
        __syncthreads();
    }
    if (which == 0) {
        u16* outp = qb + (size_t)t * INC * DK;
        #pragma unroll
        for (int mt = 0; mt < 2; ++mt)
            #pragma unroll
            for (int nt = 0; nt < 4; ++nt)
                #pragma unroll
                for (int r = 0; r < 4; ++r) {
                    int m_out = m0 + w * 32 + mt * 16 + quad * 4 + r;
                    int n_out = n0 + nt * 16 + l15;
                    outp[(size_t)m_out * DK + n_out] = f2bf(phi_f(acc[mt][nt][r]));
                }
    } else {
        u16* outp = ((which == 1) ? klt : krt) + (size_t)t * DK * INC;
        #pragma unroll
        for (int mt = 0; mt < 2; ++mt)
            #pragma unroll
            for (int nt = 0; nt < 4; ++nt)
                #pragma unroll
                for (int r = 0; r < 4; ++r) {
                    int mloc = w * 32 + mt * 16 + quad * 4 + r;
                    int nloc = nt * 16 + l15;
                    smem[nloc * 136 + mloc] = f2bf(phi_f(acc[mt][nt][r]));
                }
        __syncthreads();
        int dkl = tid >> 2, seg = tid & 3;
        const uint4* sp = (const uint4*)&smem[dkl * 136 + seg * 32];
        uint4* dp = (uint4*)&outp[(size_t)(n0 + dkl) * INC + m0 + seg * 32];
        dp[0] = sp[0]; dp[1] = sp[1]; dp[2] = sp[2]; dp[3] = sp[3];
    }
}

// ---------------- K2b: ksum[dk] = sum_n KL[n][dk] (row sums of KLt)
__global__ void k2b_ksum(const u16* __restrict__ klt, const u16* __restrict__ krt,
                         float* __restrict__ ksuml, float* __restrict__ ksumr) {
    int t = blockIdx.x; int dk = threadIdx.x;
    const u16* pl = klt + ((size_t)t * DK + dk) * INC;
    const u16* pr = krt + ((size_t)t * DK + dk) * INC;
    float s1 = 0.f, s2 = 0.f;
    for (int n = 0; n < INC; ++n) { s1 += bf2f(pl[n]); s2 += bf2f(pr[n]); }
    ksuml[t * DK + dk] = s1; ksumr[t * DK + dk] = s2;
}

// ---------------- K2c: z[n] = q[n,:].ksum + 1e-6
__global__ void k2c_z(const u16* __restrict__ qb, const float* __restrict__ ksuml,
                      const float* __restrict__ ksumr, float* __restrict__ zl, float* __restrict__ zr) {
    int t = blockIdx.x; int n = threadIdx.x;
    const u16* q = qb + ((size_t)t * INC + n) * DK;
    const float* sl = ksuml + t * DK;
    const float* sr = ksumr + t * DK;
    float a = 0.f, b = 0.f;
    for (int k = 0; k < DK; ++k) { float qv = bf2f(q[k]); a = fmaf(qv, sl[k], a); b = fmaf(qv, sr[k], b); }
    zl[t * INC + n] = a + 1e-6f;
    zr[t * INC + n] = b + 1e-6f;
}

// ---------------- K2: KVt[d][dk] = xT @ KLt-frag. M=1024,N=128,K=512.
__global__ __launch_bounds__(256) void k2_kv(const u16* __restrict__ xT,
        const u16* __restrict__ klt, const u16* __restrict__ krt,
        u16* __restrict__ kvlT, u16* __restrict__ kvrT) {
    __shared__ u16 As[128 * 40];
    __shared__ u16 Bs[64 * 40];
    int z = blockIdx.z, t = z >> 1, side = z & 1;
    const u16* A = xT + (size_t)(side ? t + 2 : t) * FD * INC;
    const u16* Bw = (side ? krt : klt) + (size_t)t * DK * INC;
    u16* outp = (side ? kvrT : kvlT) + (size_t)t * FD * DK;
    int n0 = blockIdx.x * 64, m0 = blockIdx.y * 128;
    int tid = threadIdx.x, w = tid >> 6, lane = tid & 63, l15 = lane & 15, quad = lane >> 4;
    int sm = tid >> 2, sq = (tid & 3) * 8;
    floatx4 acc[2][4];
    #pragma unroll
    for (int i = 0; i < 2; ++i)
        #pragma unroll
        for (int j = 0; j < 4; ++j) acc[i][j] = (floatx4){0.f,0.f,0.f,0.f};
    for (int k0 = 0; k0 < INC; k0 += 32) {
        *(uint4*)&As[sm * 40 + sq] = *(const uint4*)&A[(size_t)(m0 + sm) * INC + k0 + sq];
        *(uint4*)&As[(64 + sm) * 40 + sq] = *(const uint4*)&A[(size_t)(m0 + 64 + sm) * INC + k0 + sq];
        *(uint4*)&Bs[sm * 40 + sq] = *(const uint4*)&Bw[(size_t)(n0 + sm) * INC + k0 + sq];
        __syncthreads();
        shortx8 bfr[4];
        #pragma unroll
        for (int nt = 0; nt < 4; ++nt)
            bfr[nt] = *(const shortx8*)&Bs[(nt * 16 + l15) * 40 + quad * 8];
        #pragma unroll
        for (int mt = 0; mt < 2; ++mt) {
            shortx8 af = *(const shortx8*)&As[(w * 32 + mt * 16 + l15) * 40 + quad * 8];
            #pragma unroll
            for (int nt = 0; nt < 4; ++nt)
                acc[mt][nt] = __builtin_amdgcn_mfma_f32_16x16x32_bf16(af, bfr[nt], acc[mt][nt], 0, 0, 0);
        }
        __syncthreads();
    }
    #pragma unroll
    for (int mt = 0; mt < 2; ++mt)
        #pragma unroll
        for (int nt = 0; nt < 4; ++nt)
            #pragma unroll
            for (int r = 0; r < 4; ++r) {
                int m_out = m0 + w * 32 + mt * 16 + quad * 4 + r;
                int n_out = n0 + nt * 16 + l15;
                outp[(size_t)m_out * DK + n_out] = f2bf(acc[mt][nt][r]);
            }
}

// ---------------- K3: newT[d][n] = KVtL@Q^T/zl + KVtR@Q^T/zr + xT. M=1024,N=512,K=128.
__global__ __launch_bounds__(256) void k3_out(const u16* __restrict__ xT,
        const u16* __restrict__ qb, const u16* __restrict__ kvlT, const u16* __restrict__ kvrT,
        const float* __restrict__ zl, const float* __restrict__ zr, u16* __restrict__ newT) {
    __shared__ u16 As1[128 * 40];
    __shared__ u16 As2[128 * 40];
    __shared__ u16 Bs[64 * 40];
    int t = blockIdx.z;
    const u16* A1 = kvlT + (size_t)t * FD * DK;
    const u16* A2 = kvrT + (size_t)t * FD * DK;
    const u16* Bq = qb + (size_t)t * INC * DK;
    int n0 = blockIdx.x * 64, m0 = blockIdx.y * 128;
    int tid = threadIdx.x, w = tid >> 6, lane = tid & 63, l15 = lane & 15, quad = lane >> 4;
    int sm = tid >> 2, sq = (tid & 3) * 8;
    floatx4 accl[2][4], accr[2][4];
    #pragma unroll
    for (int i = 0; i < 2; ++i)
        #pragma unroll
        for (int j = 0; j < 4; ++j) {
            accl[i][j] = (floatx4){0.f,0.f,0.f,0.f};
            accr[i][j] = (floatx4){0.f,0.f,0.f,0.f};
        }
    for (int k0 = 0; k0 < DK; k0 += 32) {
        *(uint4*)&As1[sm * 40 + sq] = *(const uint4*)&A1[(size_t)(m0 + sm) * DK + k0 + sq];
        *(uint4*)&As1[(64 + sm) * 40 + sq] = *(const uint4*)&A1[(size_t)(m0 + 64 + sm) * DK + k0 + sq];
        *(uint4*)&As2[sm * 40 + sq] = *(const uint4*)&A2[(size_t)(m0 + sm) * DK + k0 + sq];
        *(uint4*)&As2[(64 + sm) * 40 + sq] = *(const uint4*)&A2[(size_t)(m0 + 64 + sm) * DK + k0 + sq];
        *(uint4*)&Bs[sm * 40 + sq] = *(const uint4*)&Bq[(size_t)(n0 + sm) * DK + k0 + sq];
        __syncthreads();
        shortx8 bfr[4];
        #pragma unroll
        for (int nt = 0; nt < 4; ++nt)
            bfr[nt] = *(const shortx8*)&Bs[(nt * 16 + l15) * 40 + quad * 8];
        #pragma unroll
        for (int mt = 0; mt < 2; ++mt) {
            shortx8 afl = *(const shortx8*)&As1[(w * 32 + mt * 16 + l15) * 40 + quad * 8];
            shortx8 afr = *(const shortx8*)&As2[(w * 32 + mt * 16 + l15) * 40 + quad * 8];
            #pragma unroll
            for (int nt = 0; nt < 4; ++nt) {
                accl[mt][nt] = __builtin_amdgcn_mfma_f32_16x16x32_bf16(afl, bfr[nt], accl[mt][nt], 0, 0, 0);
                accr[mt][nt] = __builtin_amdgcn_mfma_f32_16x16x32_bf16(afr, bfr[nt], accr[mt][nt], 0, 0, 0);
            }
        }
        __syncthreads();
    }
    float il[4], ir[4];
    #pragma unroll
    for (int nt = 0; nt < 4; ++nt) {
        int n_out = n0 + nt * 16 + l15;
        il[nt] = 1.0f / zl[t * INC + n_out];
        ir[nt] = 1.0f / zr[t * INC + n_out];
    }
    const u16* xc = xT + (size_t)(t + 1) * FD * INC;
    u16* outp = newT + (size_t)t * FD * INC;
    #pragma unroll
    for (int mt = 0; mt < 2; ++mt)
        #pragma unroll
        for (int nt = 0; nt < 4; ++nt)
            #pragma unroll
            for (int r = 0; r < 4; ++r) {
                int m_out = m0 + w * 32 + mt * 16 + quad * 4 + r;
                int n_out = n0 + nt * 16 + l15;
                float xv = bf2f(xc[(size_t)m_out * INC + n_out]);
                float v = xv + accl[mt][nt][r] * il[nt] + accr[mt][nt][r] * ir[nt];
                outp[(size_t)m_out * INC + n_out] = f2bf(v);
            }
}

// ---------------- K4: upT[px][m] = newT @ upwT; gate fused via LDS-transposed epilogue.
__global__ __launch_bounds__(256) void k4_up(const u16* __restrict__ xT,
        const u16* __restrict__ newT, const u16* __restrict__ upwT,
        const float* __restrict__ up_b, u16* __restrict__ P) {
    __shared__ u16 smem[12288];   // GEMM: As 5120 + Bs 2560 u16; epilogue Ts: 512*24 u16
    u16* As = smem;
    u16* Bs = smem + 5120;
    int b = blockIdx.z;
    const u16* A = (b == 0) ? xT
                 : (b == B_ - 1) ? (xT + (size_t)(B_ - 1) * FD * INC)
                 : (newT + (size_t)(b - 1) * FD * INC);
    int n0 = blockIdx.x * 64, m0 = blockIdx.y * 128;
    int tid = threadIdx.x, w = tid >> 6, lane = tid & 63, l15 = lane & 15, quad = lane >> 4;
    int sm = tid >> 2, sq = (tid & 3) * 8;
    floatx4 acc[2][4];
    #pragma unroll
    for (int i = 0; i < 2; ++i)
        #pragma unroll
        for (int j = 0; j < 4; ++j) acc[i][j] = (floatx4){0.f,0.f,0.f,0.f};
    for (int k0 = 0; k0 < INC; k0 += 32) {
        *(uint4*)&As[sm * 40 + sq] = *(const uint4*)&A[(size_t)(m0 + sm) * INC + k0 + sq];
        *(uint4*)&As[(64 + sm) * 40 + sq] = *(const uint4*)&A[(size_t)(m0 + 64 + sm) * INC + k0 + sq];
        *(uint4*)&Bs[sm * 40 + sq] = *(const uint4*)&upwT[(size_t)(n0 + sm) * INC + k0 + sq];
        __syncthreads();
        shortx8 bfr[4];
        #pragma unroll
        for (int nt = 0; nt < 4; ++nt)
            bfr[nt] = *(const shortx8*)&Bs[(nt * 16 + l15) * 40 + quad * 8];
        #pragma unroll
        for (int mt = 0; mt < 2; ++mt) {
            shortx8 af = *(const shortx8*)&As[(w * 32 + mt * 16 + l15) * 40 + quad * 8];
            #pragma unroll
            for (int nt = 0; nt < 4; ++nt)
                acc[mt][nt] = __builtin_amdgcn_mfma_f32_16x16x32_bf16(af, bfr[nt], acc[mt][nt], 0, 0, 0);
        }
        __syncthreads();
    }
    // epilogue: stage up+bias into Ts[pi*24 + o_rel], pi = (l15&3)*128 + local_px
    u16* Ts = smem;
    int ppos = (l15 & 3) * 128;
    #pragma unroll
    for (int mt = 0; mt < 2; ++mt)
        #pragma unroll
        for (int nt = 0; nt < 4; ++nt) {
            int lm = nt * 16 + l15;
            float bias = up_b[(n0 + lm) >> 2];
            int o_rel = lm >> 2;
            #pragma unroll
            for (int r = 0; r < 4; ++r) {
                int l = w * 32 + mt * 16 + quad * 4 + r;
                Ts[(ppos + l) * 24 + o_rel] = f2bf(acc[mt][nt][r] + bias);
            }
        }
    __syncthreads();
    // write-out: each thread = 2 (pixel, 16-channel strip) jobs, fully vectorized
    #pragma unroll
    for (int j2 = 0; j2 < 2; ++j2) {
        int pi = tid + j2 * 256;
        int pp = pi >> 7, l = pi & 127;
        int aa = pp >> 1, cbb = pp & 1;
        int px = m0 + l;
        int row = 2 * (px >> 5) + aa, colq = 2 * (px & 31) + cbb;
        size_t dst = ((size_t)(b * 66 + 1 + row) * 66 + 1 + colq) * 512 + (n0 >> 2);
        union { uint4 v; u16 h[8]; } a0, a1, s0, s1, g0, g1;
        a0.v = *(const uint4*)&Ts[pi * 24];
        a1.v = *(const uint4*)&Ts[pi * 24 + 8];
        s0.v = *(const uint4*)(P + dst + 256);
        s1.v = *(const uint4*)(P + dst + 256 + 8);
        #pragma unroll
        for (int e = 0; e < 8; ++e) {
            float r0 = fmaxf(bf2f(a0.h[e]) + bf2f(s0.h[e]), 0.0f);
            float r1 = fmaxf(bf2f(a1.h[e]) + bf2f(s1.h[e]), 0.0f);
            g0.h[e] = f2bf(1.0f / (1.0f + expf(-r0)));
            g1.h[e] = f2bf(1.0f / (1.0f + expf(-r1)));
        }
        *(uint4*)(P + dst) = g0.v;
        *(uint4*)(P + dst + 8) = g1.v;
    }
}

// ---------------- K4b: skip s -> bf16 into padded P (channels 256..511)
__global__ __launch_bounds__(256) void k4b_sfill(const float* __restrict__ s_in,
                                                 u16* __restrict__ P) {
    __shared__ u16 T[64 * 264];
    int p = blockIdx.x;
    int b = blockIdx.y;
    int tid = threadIdx.x;
    int qcol = tid & 63;
    int ob = tid >> 6;
    for (int o = ob; o < 256; o += 4) {
        float v = s_in[((size_t)(b * OUTC + o) * HO + p) * WO + qcol];
        T[qcol * 264 + o] = f2bf(v);
    }
    __syncthreads();
    int q2 = tid >> 2;
    int sg = tid & 3;
    size_t base = ((size_t)(b * 66 + 1 + p) * 66 + 1 + q2) * 512 + 256;
    #pragma unroll
    for (int it = 0; it < 8; ++it) {
        int seg = sg + it * 4;
        uint4 v = *(const uint4*)&T[q2 * 264 + seg * 8];
        *(uint4*)(P + base + seg * 8) = v;
    }
}

// ---------------- K5: conv3x3 MFMA implicit GEMM, async global_load_lds staging
__global__ __launch_bounds__(256) void k5_mfma(const u16* __restrict__ P,
        const u16* __restrict__ Wt, const float* __restrict__ c1_b,
        float* __restrict__ y) {
    __shared__ u16 Xs[6 * 66 * KC5];   // 12672 u16 = 25344 B, linear s*16B layout
    int rb = blockIdx.x;
    int o0 = blockIdx.y * 64;
    int b  = blockIdx.z;
    int tid = threadIdx.x;
    int w = tid >> 6, lane = tid & 63;
    int l15 = lane & 15, quad = lane >> 4;

    floatx4 acc[4][4];
    #pragma unroll
    for (int i = 0; i < 4; ++i)
        #pragma unroll
        for (int j = 0; j < 4; ++j)
            acc[i][j] = (floatx4){0.f, 0.f, 0.f, 0.f};

    size_t Pbase = ((size_t)b * 66 + (size_t)rb * 4) * 66 * 512;

    for (int ch = 0; ch < 16; ++ch) {
        int c0 = ch * 32;
        __syncthreads();
        // async stage: slab slot s (16B) <- P[pixel(r,col)][c0 + cs*8 ..], s = (r*264 + col*4 + cs)
        #pragma unroll
        for (int it = 0; it < 7; ++it) {
            int s = it * 256 + tid;
            if (s < 1584) {
                int r = s / 264, rem = s - r * 264;
                int col = rem >> 2, cs = rem & 3;
                const u16* gp = P + Pbase + ((size_t)r * 66 + col) * 512 + c0 + cs * 8;
                __builtin_amdgcn_global_load_lds(
                    (const __attribute__((address_space(1))) void*)gp,
                    (__attribute__((address_space(3))) void*)&Xs[(size_t)(it * 256 + w * 64) * 8],
                    16, 0, 0);
            }
        }
        __syncthreads();
        #pragma unroll
        for (int dy = 0; dy < 3; ++dy) {
            #pragma unroll
            for (int dx = 0; dx < 3; ++dx) {
                int tap = dy * 3 + dx;
                shortx8 wf[4];
                #pragma unroll
                for (int nt = 0; nt < 4; ++nt)
                    wf[nt] = *(const shortx8*)(Wt +
                        ((size_t)(tap * 256 + o0 + nt * 16 + l15)) * 512 + c0 + quad * 8);
                #pragma unroll
                for (int mt = 0; mt < 4; ++mt) {
                    shortx8 af = *(const shortx8*)&Xs[((w + dy) * 66 + mt * 16 + l15 + dx) * KC5 + quad * 8];
                    #pragma unroll
                    for (int nt = 0; nt < 4; ++nt)
                        acc[mt][nt] = __builtin_amdgcn_mfma_f32_16x16x32_bf16(
                            af, wf[nt], acc[mt][nt], 0, 0, 0);
                }
            }
        }
    }
    int row = rb * 4 + w;
    float bias[4];
    #pragma unroll
    for (int nt = 0; nt < 4; ++nt) bias[nt] = c1_b[o0 + nt * 16 + l15];
    #pragma unroll
    for (int mt = 0; mt < 4; ++mt) {
        #pragma unroll
        for (int nt = 0; nt < 4; ++nt) {
            int o = o0 + nt * 16 + l15;
            size_t ybase = (size_t)(b * OUTC + o) * SP + row * 64;
            #pragma unroll
            for (int r = 0; r < 4; ++r) {
                int col = mt * 16 + quad * 4 + r;
                y[ybase + col] = acc[mt][nt][r] + bias[nt];
            }
        }
    }
}

// ---------------- K6: BN stats reduce
__global__ __launch_bounds__(256) void k6_bnred(const float* __restrict__ y,
        float* __restrict__ bnsum, float* __restrict__ bnsq) {
    int b = blockIdx.x, o = blockIdx.y;
    const float* p = y + ((size_t)b * OUTC + o) * SP;
    float s1 = 0.f, s2 = 0.f;
    for (int i = threadIdx.x; i < SP; i += 256) { float v = p[i]; s1 += v; s2 = fmaf(v, v, s2); }
    #pragma unroll
    for (int off = 32; off > 0; off >>= 1) {
        s1 += __shfl_down(s1, off, 64);
        s2 += __shfl_down(s2, off, 64);
    }
    __shared__ float r1[4], r2[4];
    int wid = threadIdx.x >> 6, lane = threadIdx.x & 63;
    if (lane == 0) { r1[wid] = s1; r2[wid] = s2; }
    __syncthreads();
    if (threadIdx.x == 0) {
        atomicAdd(&bnsum[o], r1[0] + r1[1] + r1[2] + r1[3]);
        atomicAdd(&bnsq[o],  r2[0] + r2[1] + r2[2] + r2[3]);
    }
}

// ---------------- K7: BN finalize
__global__ void k7_bnfin(const float* __restrict__ bnsum, const float* __restrict__ bnsq,
                         const float* __restrict__ bn_g, const float* __restrict__ bn_b,
                         float* __restrict__ scale, float* __restrict__ shift) {
    int o = threadIdx.x;
    float cnt = (float)(B_ * SP);
    float mu = bnsum[o] / cnt;
    float var = bnsq[o] / cnt - mu * mu;
    float sc = bn_g[o] * rsqrtf(var + 1e-5f);
    scale[o] = sc;
    shift[o] = bn_b[o] - mu * sc;
}

// ---------------- K8: BN apply + relu
__global__ __launch_bounds__(256) void k8_apply(float* __restrict__ y,
        const float* __restrict__ scale, const float* __restrict__ shift) {
    int i = blockIdx.x * 256 + threadIdx.x;
    int o = (i >> 10) & 255;
    float4 v = ((float4*)y)[i];
    float sc = scale[o], sh = shift[o];
    v.x = fmaxf(fmaf(v.x, sc, sh), 0.f);
    v.y = fmaxf(fmaf(v.y, sc, sh), 0.f);
    v.z = fmaxf(fmaf(v.z, sc, sh), 0.f);
    v.w = fmaxf(fmaf(v.w, sc, sh), 0.f);
    ((float4*)y)[i] = v;
}

extern "C" void kernel_launch(void* const* d_in, const int* in_sizes, int n_in,
                              void* d_out, int out_size, void* d_ws, size_t ws_size,
                              hipStream_t stream) {
    const float* x    = (const float*)d_in[0];
    const float* s_in = (const float*)d_in[1];
    const float* up_w = (const float*)d_in[2];
    const float* up_b = (const float*)d_in[3];
    const float* wq   = (const float*)d_in[4];
    const float* wkl  = (const float*)d_in[5];
    const float* wkr  = (const float*)d_in[6];
    const float* c1_w = (const float*)d_in[7];
    const float* c1_b = (const float*)d_in[8];
    const float* bn_g = (const float*)d_in[9];
    const float* bn_b = (const float*)d_in[10];
    float* y = (float*)d_out;
    float* ws = (float*)d_ws;

    size_t off = 0;
    float* ksuml = ws + off; off += (size_t)T_ * DK;
    float* ksumr = ws + off; off += (size_t)T_ * DK;
    float* zl    = ws + off; off += (size_t)T_ * INC;
    float* zr    = ws + off; off += (size_t)T_ * INC;
    float* bnsum = ws + off; off += OUTC;
    float* bnsq  = ws + off; off += OUTC;
    float* scale = ws + off; off += OUTC;
    float* shift = ws + off; off += OUTC;

    u16* ub = (u16*)(ws + off);
    size_t uo = 0;
    u16* qb   = ub + uo; uo += (size_t)T_ * INC * DK;
    u16* klt  = ub + uo; uo += (size_t)T_ * DK * INC;
    u16* krt  = ub + uo; uo += (size_t)T_ * DK * INC;
    u16* kvlT = ub + uo; uo += (size_t)T_ * FD * DK;
    u16* kvrT = ub + uo; uo += (size_t)T_ * FD * DK;
    u16* newT = ub + uo; uo += (size_t)T_ * FD * INC;
    u16* xT   = ub + uo; uo += (size_t)B_ * FD * INC;
    u16* wqT  = ub + uo; uo += (size_t)DK * FD;
    u16* wklT = ub + uo; uo += (size_t)DK * FD;
    u16* wkrT = ub + uo; uo += (size_t)DK * FD;
    u16* upwT = ub + uo; uo += (size_t)FD * INC;
    u16* Wt   = ub + uo; uo += (size_t)9 * OUTC * 2 * INC;
    u16* P    = ub + uo; uo += (size_t)B_ * 66 * 66 * 512;

    hipMemsetAsync(bnsum, 0, 2 * OUTC * sizeof(float), stream);

    kborder<<<dim3(13, B_), dim3(256), 0, stream>>>(P);
    kprep_x<<<dim3(16, 8, B_), dim3(256), 0, stream>>>(x, xT);
    ktr_w<<<dim3(2, 16), dim3(256), 0, stream>>>(wq, wqT, FD, DK);
    ktr_w<<<dim3(2, 16), dim3(256), 0, stream>>>(wkl, wklT, FD, DK);
    ktr_w<<<dim3(2, 16), dim3(256), 0, stream>>>(wkr, wkrT, FD, DK);
    ktr_w<<<dim3(16, 8), dim3(256), 0, stream>>>(up_w, upwT, INC, FD);
    kw_tr<<<dim3((256 * 512 * 9 + 255) / 256), dim3(256), 0, stream>>>(c1_w, Wt);

    k1_proj<<<dim3(2, 4, 42), dim3(256), 0, stream>>>(x, wqT, wklT, wkrT, qb, klt, krt);
    k2b_ksum<<<dim3(T_), dim3(DK), 0, stream>>>(klt, krt, ksuml, ksumr);
    k2c_z<<<dim3(T_), dim3(INC), 0, stream>>>(qb, ksuml, ksumr, zl, zr);
    k2_kv<<<dim3(2, 8, 28), dim3(256), 0, stream>>>(xT, klt, krt, kvlT, kvrT);
    k3_out<<<dim3(8, 8, T_), dim3(256), 0, stream>>>(xT, qb, kvlT, kvrT, zl, zr, newT);
    k4b_sfill<<<dim3(64, B_), dim3(256), 0, stream>>>(s_in, P);
    k4_up<<<dim3(16, 8, B_), dim3(256), 0, stream>>>(xT, newT, upwT, up_b, P);
    k5_mfma<<<dim3(16, 4, B_), dim3(256), 0, stream>>>(P, Wt, c1_b, y);
    k6_bnred<<<dim3(B_, OUTC), dim3(256), 0, stream>>>(y, bnsum, bnsq);
    k7_bnfin<<<dim3(1), dim3(OUTC), 0, stream>>>(bnsum, bnsq, bn_g, bn_b, scale, shift);
    k8_apply<<<dim3((B_ * OUTC * SP / 4) / 256), dim3(256), 0, stream>>>(y, scale, shift);
}

// Round 5
// 681.395 us; speedup vs baseline: 5.1254x; 1.0091x over previous
//
#include <hip/hip_runtime.h>
#include <math.h>

#define B_ 16
#define INC 512
#define OUTC 256
#define FD 1024
#define DK 128
#define T_ 14
#define HO 64
#define WO 64
#define SP (HO*WO)
#define KC5P 40   // padded channel stride (u16) in conv X slab: 80B pixel stride -> 4-way max alias

typedef unsigned short u16;
typedef __attribute__((ext_vector_type(8))) short shortx8;
typedef __attribute__((ext_vector_type(4))) float floatx4;

__device__ __forceinline__ float phi_f(float t) {
    return t > 0.0f ? t + 1.0f : expf(t);
}
__device__ __forceinline__ u16 f2bf(float f) {
    unsigned int u = __float_as_uint(f);
    unsigned int r = (u + 0x7fffu + ((u >> 16) & 1u)) >> 16;
    return (u16)r;
}
__device__ __forceinline__ float bf2f(u16 h) {
    return __uint_as_float(((unsigned int)h) << 16);
}

// ---------------- prep: xT[b][d][c] bf16 from x[b][c][d] fp32
__global__ __launch_bounds__(256) void kprep_x(const float* __restrict__ x, u16* __restrict__ xT) {
    __shared__ u16 T[64][65];
    int d0 = blockIdx.x * 64, c0 = blockIdx.y * 64, b = blockIdx.z;
    const float* src = x + (size_t)b * INC * FD;
    int tid = threadIdx.x, lr = tid >> 6, lc = tid & 63;
    #pragma unroll
    for (int i = 0; i < 16; ++i) {
        int c = lr + i * 4;
        T[lc][c] = f2bf(src[(size_t)(c0 + c) * FD + d0 + lc]);
    }
    __syncthreads();
    u16* dst = xT + (size_t)b * FD * INC;
    #pragma unroll
    for (int i = 0; i < 16; ++i) {
        int d = lr + i * 4;
        dst[(size_t)(d0 + d) * INC + c0 + lc] = T[d][lc];
    }
}

// ---------------- prep: generic transpose fp32[R][C] -> bf16[C][R]
__global__ __launch_bounds__(256) void ktr_w(const float* __restrict__ src, u16* __restrict__ dst,
                                             int R, int C) {
    __shared__ u16 T[64][65];
    int c0 = blockIdx.x * 64, r0 = blockIdx.y * 64;
    int tid = threadIdx.x, lr = tid >> 6, lc = tid & 63;
    #pragma unroll
    for (int i = 0; i < 16; ++i) {
        int r = lr + i * 4;
        T[lc][r] = f2bf(src[(size_t)(r0 + r) * C + c0 + lc]);
    }
    __syncthreads();
    #pragma unroll
    for (int i = 0; i < 16; ++i) {
        int c = lr + i * 4;
        dst[(size_t)(c0 + c) * R + r0 + lc] = T[c][lc];
    }
}

// ---------------- prep: conv weights to Wt[tap][o][c] bf16
__global__ void kw_tr(const float* __restrict__ c1_w, u16* __restrict__ Wt) {
    int i = blockIdx.x * 256 + threadIdx.x;
    if (i >= 256 * 512 * 9) return;
    int tap = i % 9; int t2 = i / 9;
    int c = t2 % 512; int o = t2 / 512;
    Wt[((size_t)tap * 256 + o) * 512 + c] = f2bf(c1_w[i]);
}

// ---------------- prep: zero only the border ring of padded P
__global__ __launch_bounds__(256) void kborder(u16* __restrict__ P) {
    int b = blockIdx.y;
    int cbase = blockIdx.x * 20;
    uint4 z = {0, 0, 0, 0};
    for (int i = threadIdx.x; i < 20 * 64; i += 256) {
        int c = cbase + (i >> 6);
        int sub = i & 63;
        int row, col;
        if (c < 66)       { row = 0;       col = c; }
        else if (c < 132) { row = 65;      col = c - 66; }
        else if (c < 196) { row = c - 131; col = 0; }
        else              { row = c - 195; col = 65; }
        *(uint4*)(P + ((size_t)(b * 66 + row) * 66 + col) * 512 + sub * 8) = z;
    }
}

// ---------------- K1: Q/KL/KR = phi(X @ W) via MFMA. M=512,N=128,K=1024.
__global__ __launch_bounds__(256) void k1_proj(const float* __restrict__ x,
        const u16* __restrict__ wqT, const u16* __restrict__ wklT, const u16* __restrict__ wkrT,
        u16* __restrict__ qb, u16* __restrict__ klt, u16* __restrict__ krt) {
    __shared__ u16 smem[8704];
    u16* As = smem;
    u16* Bs = smem + 5120;
    int z = blockIdx.z, t = z / 3, which = z - t * 3;
    int src = (which == 0) ? t + 1 : (which == 1 ? t : t + 2);
    const float* Af = x + (size_t)src * INC * FD;
    const u16* Bw = (which == 0) ? wqT : (which == 1 ? wklT : wkrT);
    int n0 = blockIdx.x * 64, m0 = blockIdx.y * 128;
    int tid = threadIdx.x, w = tid >> 6, lane = tid & 63, l15 = lane & 15, quad = lane >> 4;
    int sm = tid >> 2, sq = (tid & 3) * 8;
    floatx4 acc[2][4];
    #pragma unroll
    for (int i = 0; i < 2; ++i)
        #pragma unroll
        for (int j = 0; j < 4; ++j) acc[i][j] = (floatx4){0.f,0.f,0.f,0.f};

    for (int k0 = 0; k0 < FD; k0 += 32) {
        float4 v0 = *(const float4*)&Af[(size_t)(m0 + sm) * FD + k0 + sq];
        float4 v1 = *(const float4*)&Af[(size_t)(m0 + sm) * FD + k0 + sq + 4];
        float4 v2 = *(const float4*)&Af[(size_t)(m0 + 64 + sm) * FD + k0 + sq];
        float4 v3 = *(const float4*)&Af[(size_t)(m0 + 64 + sm) * FD + k0 + sq + 4];
        union { u16 h[8]; uint4 v; } p0, p1;
        p0.h[0]=f2bf(v0.x); p0.h[1]=f2bf(v0.y); p0.h[2]=f2bf(v0.z); p0.h[3]=f2bf(v0.w);
        p0.h[4]=f2bf(v1.x); p0.h[5]=f2bf(v1.y); p0.h[6]=f2bf(v1.z); p0.h[7]=f2bf(v1.w);
        p1.h[0]=f2bf(v2.x); p1.h[1]=f2bf(v2.y); p1.h[2]=f2bf(v2.z); p1.h[3]=f2bf(v2.w);
        p1.h[4]=f2bf(v3.x); p1.h[5]=f2bf(v3.y); p1.h[6]=f2bf(v3.z); p1.h[7]=f2bf(v3.w);
        *(uint4*)&As[sm * 40 + sq] = p0.v;
        *(uint4*)&As[(64 + sm) * 40 + sq] = p1.v;
        *(uint4*)&Bs[sm * 40 + sq] = *(const uint4*)&Bw[(size_t)(n0 + sm) * FD + k0 + sq];
        __syncthreads();
        shortx8 bfr[4];
        #pragma unroll
        for (int nt = 0; nt < 4; ++nt)
            bfr[nt] = *(const shortx8*)&Bs[(nt * 16 + l15) * 40 + quad * 8];
        #pragma unroll
        for (int mt = 0; mt < 2; ++mt) {
            shortx8 af = *(const shortx8*)&As[(w * 32 + mt * 16 + l15) * 40 + quad * 8];
            #pragma unroll
            for (int nt = 0; nt < 4; ++nt)
                acc[mt][nt] = __builtin_amdgcn_mfma_f32_16x16x32_bf16(af, bfr[nt], acc[mt][nt], 0, 0, 0);
        }
        __syncthreads();
    }
    if (which == 0) {
        u16* outp = qb + (size_t)t * INC * DK;
        #pragma unroll
        for (int mt = 0; mt < 2; ++mt)
            #pragma unroll
            for (int nt = 0; nt < 4; ++nt)
                #pragma unroll
                for (int r = 0; r < 4; ++r) {
                    int m_out = m0 + w * 32 + mt * 16 + quad * 4 + r;
                    int n_out = n0 + nt * 16 + l15;
                    outp[(size_t)m_out * DK + n_out] = f2bf(phi_f(acc[mt][nt][r]));
                }
    } else {
        u16* outp = ((which == 1) ? klt : krt) + (size_t)t * DK * INC;
        #pragma unroll
        for (int mt = 0; mt < 2; ++mt)
            #pragma unroll
            for (int nt = 0; nt < 4; ++nt)
                #pragma unroll
                for (int r = 0; r < 4; ++r) {
                    int mloc = w * 32 + mt * 16 + quad * 4 + r;
                    int nloc = nt * 16 + l15;
                    smem[nloc * 136 + mloc] = f2bf(phi_f(acc[mt][nt][r]));
                }
        __syncthreads();
        int dkl = tid >> 2, seg = tid & 3;
        const uint4* sp = (const uint4*)&smem[dkl * 136 + seg * 32];
        uint4* dp = (uint4*)&outp[(size_t)(n0 + dkl) * INC + m0 + seg * 32];
        dp[0] = sp[0]; dp[1] = sp[1]; dp[2] = sp[2]; dp[3] = sp[3];
    }
}

// ---------------- K2b: ksum[dk] += sum_n KL[n][dk]; parallel over n-blocks, vectorized
__global__ __launch_bounds__(128) void k2b_ksum(const u16* __restrict__ klt, const u16* __restrict__ krt,
                         float* __restrict__ ksuml, float* __restrict__ ksumr) {
    int t = blockIdx.x, nb = blockIdx.y;
    int dk = threadIdx.x;
    const u16* pl = klt + ((size_t)t * DK + dk) * INC + nb * 64;
    const u16* pr = krt + ((size_t)t * DK + dk) * INC + nb * 64;
    float s1 = 0.f, s2 = 0.f;
    #pragma unroll
    for (int i = 0; i < 8; ++i) {
        union { uint4 v; u16 h[8]; } a, b;
        a.v = *(const uint4*)(pl + i * 8);
        b.v = *(const uint4*)(pr + i * 8);
        #pragma unroll
        for (int e = 0; e < 8; ++e) { s1 += bf2f(a.h[e]); s2 += bf2f(b.h[e]); }
    }
    atomicAdd(&ksuml[t * DK + dk], s1);
    atomicAdd(&ksumr[t * DK + dk], s2);
}

// ---------------- K2c: z[n] = q[n,:].ksum + 1e-6 (vectorized q reads)
__global__ __launch_bounds__(512) void k2c_z(const u16* __restrict__ qb, const float* __restrict__ ksuml,
                      const float* __restrict__ ksumr, float* __restrict__ zl, float* __restrict__ zr) {
    int t = blockIdx.x; int n = threadIdx.x;
    const uint4* qp = (const uint4*)(qb + ((size_t)t * INC + n) * DK);
    const float* sl = ksuml + t * DK;
    const float* sr = ksumr + t * DK;
    float a = 0.f, b = 0.f;
    #pragma unroll
    for (int k16 = 0; k16 < 16; ++k16) {
        union { uint4 v; u16 h[8]; } q;
        q.v = qp[k16];
        #pragma unroll
        for (int e = 0; e < 8; ++e) {
            float qv = bf2f(q.h[e]);
            a = fmaf(qv, sl[k16 * 8 + e], a);
            b = fmaf(qv, sr[k16 * 8 + e], b);
        }
    }
    zl[t * INC + n] = a + 1e-6f;
    zr[t * INC + n] = b + 1e-6f;
}

// ---------------- K2: KVt[d][dk] = xT @ KLt-frag. M=1024,N=128,K=512.
__global__ __launch_bounds__(256) void k2_kv(const u16* __restrict__ xT,
        const u16* __restrict__ klt, const u16* __restrict__ krt,
        u16* __restrict__ kvlT, u16* __restrict__ kvrT) {
    __shared__ u16 As[128 * 40];
    __shared__ u16 Bs[64 * 40];
    int z = blockIdx.z, t = z >> 1, side = z & 1;
    const u16* A = xT + (size_t)(side ? t + 2 : t) * FD * INC;
    const u16* Bw = (side ? krt : klt) + (size_t)t * DK * INC;
    u16* outp = (side ? kvrT : kvlT) + (size_t)t * FD * DK;
    int n0 = blockIdx.x * 64, m0 = blockIdx.y * 128;
    int tid = threadIdx.x, w = tid >> 6, lane = tid & 63, l15 = lane & 15, quad = lane >> 4;
    int sm = tid >> 2, sq = (tid & 3) * 8;
    floatx4 acc[2][4];
    #pragma unroll
    for (int i = 0; i < 2; ++i)
        #pragma unroll
        for (int j = 0; j < 4; ++j) acc[i][j] = (floatx4){0.f,0.f,0.f,0.f};
    for (int k0 = 0; k0 < INC; k0 += 32) {
        *(uint4*)&As[sm * 40 + sq] = *(const uint4*)&A[(size_t)(m0 + sm) * INC + k0 + sq];
        *(uint4*)&As[(64 + sm) * 40 + sq] = *(const uint4*)&A[(size_t)(m0 + 64 + sm) * INC + k0 + sq];
        *(uint4*)&Bs[sm * 40 + sq] = *(const uint4*)&Bw[(size_t)(n0 + sm) * INC + k0 + sq];
        __syncthreads();
        shortx8 bfr[4];
        #pragma unroll
        for (int nt = 0; nt < 4; ++nt)
            bfr[nt] = *(const shortx8*)&Bs[(nt * 16 + l15) * 40 + quad * 8];
        #pragma unroll
        for (int mt = 0; mt < 2; ++mt) {
            shortx8 af = *(const shortx8*)&As[(w * 32 + mt * 16 + l15) * 40 + quad * 8];
            #pragma unroll
            for (int nt = 0; nt < 4; ++nt)
                acc[mt][nt] = __builtin_amdgcn_mfma_f32_16x16x32_bf16(af, bfr[nt], acc[mt][nt], 0, 0, 0);
        }
        __syncthreads();
    }
    #pragma unroll
    for (int mt = 0; mt < 2; ++mt)
        #pragma unroll
        for (int nt = 0; nt < 4; ++nt)
            #pragma unroll
            for (int r = 0; r < 4; ++r) {
                int m_out = m0 + w * 32 + mt * 16 + quad * 4 + r;
                int n_out = n0 + nt * 16 + l15;
                outp[(size_t)m_out * DK + n_out] = f2bf(acc[mt][nt][r]);
            }
}

// ---------------- K3: newT[d][n] = KVtL@Q^T/zl + KVtR@Q^T/zr + xT. M=1024,N=512,K=128.
__global__ __launch_bounds__(256) void k3_out(const u16* __restrict__ xT,
        const u16* __restrict__ qb, const u16* __restrict__ kvlT, const u16* __restrict__ kvrT,
        const float* __restrict__ zl, const float* __restrict__ zr, u16* __restrict__ newT) {
    __shared__ u16 As1[128 * 40];
    __shared__ u16 As2[128 * 40];
    __shared__ u16 Bs[64 * 40];
    int t = blockIdx.z;
    const u16* A1 = kvlT + (size_t)t * FD * DK;
    const u16* A2 = kvrT + (size_t)t * FD * DK;
    const u16* Bq = qb + (size_t)t * INC * DK;
    int n0 = blockIdx.x * 64, m0 = blockIdx.y * 128;
    int tid = threadIdx.x, w = tid >> 6, lane = tid & 63, l15 = lane & 15, quad = lane >> 4;
    int sm = tid >> 2, sq = (tid & 3) * 8;
    floatx4 accl[2][4], accr[2][4];
    #pragma unroll
    for (int i = 0; i < 2; ++i)
        #pragma unroll
        for (int j = 0; j < 4; ++j) {
            accl[i][j] = (floatx4){0.f,0.f,0.f,0.f};
            accr[i][j] = (floatx4){0.f,0.f,0.f,0.f};
        }
    for (int k0 = 0; k0 < DK; k0 += 32) {
        *(uint4*)&As1[sm * 40 + sq] = *(const uint4*)&A1[(size_t)(m0 + sm) * DK + k0 + sq];
        *(uint4*)&As1[(64 + sm) * 40 + sq] = *(const uint4*)&A1[(size_t)(m0 + 64 + sm) * DK + k0 + sq];
        *(uint4*)&As2[sm * 40 + sq] = *(const uint4*)&A2[(size_t)(m0 + sm) * DK + k0 + sq];
        *(uint4*)&As2[(64 + sm) * 40 + sq] = *(const uint4*)&A2[(size_t)(m0 + 64 + sm) * DK + k0 + sq];
        *(uint4*)&Bs[sm * 40 + sq] = *(const uint4*)&Bq[(size_t)(n0 + sm) * DK + k0 + sq];
        __syncthreads();
        shortx8 bfr[4];
        #pragma unroll
        for (int nt = 0; nt < 4; ++nt)
            bfr[nt] = *(const shortx8*)&Bs[(nt * 16 + l15) * 40 + quad * 8];
        #pragma unroll
        for (int mt = 0; mt < 2; ++mt) {
            shortx8 afl = *(const shortx8*)&As1[(w * 32 + mt * 16 + l15) * 40 + quad * 8];
            shortx8 afr = *(const shortx8*)&As2[(w * 32 + mt * 16 + l15) * 40 + quad * 8];
            #pragma unroll
            for (int nt = 0; nt < 4; ++nt) {
                accl[mt][nt] = __builtin_amdgcn_mfma_f32_16x16x32_bf16(afl, bfr[nt], accl[mt][nt], 0, 0, 0);
                accr[mt][nt] = __builtin_amdgcn_mfma_f32_16x16x32_bf16(afr, bfr[nt], accr[mt][nt], 0, 0, 0);
            }
        }
        __syncthreads();
    }
    float il[4], ir[4];
    #pragma unroll
    for (int nt = 0; nt < 4; ++nt) {
        int n_out = n0 + nt * 16 + l15;
        il[nt] = 1.0f / zl[t * INC + n_out];
        ir[nt] = 1.0f / zr[t * INC + n_out];
    }
    const u16* xc = xT + (size_t)(t + 1) * FD * INC;
    u16* outp = newT + (size_t)t * FD * INC;
    #pragma unroll
    for (int mt = 0; mt < 2; ++mt)
        #pragma unroll
        for (int nt = 0; nt < 4; ++nt)
            #pragma unroll
            for (int r = 0; r < 4; ++r) {
                int m_out = m0 + w * 32 + mt * 16 + quad * 4 + r;
                int n_out = n0 + nt * 16 + l15;
                float xv = bf2f(xc[(size_t)m_out * INC + n_out]);
                float v = xv + accl[mt][nt][r] * il[nt] + accr[mt][nt][r] * ir[nt];
                outp[(size_t)m_out * INC + n_out] = f2bf(v);
            }
}

// ---------------- K4: upT[px][m] = newT @ upwT; gate fused via LDS-transposed epilogue.
__global__ __launch_bounds__(256) void k4_up(const u16* __restrict__ xT,
        const u16* __restrict__ newT, const u16* __restrict__ upwT,
        const float* __restrict__ up_b, u16* __restrict__ P) {
    __shared__ u16 smem[12288];
    u16* As = smem;
    u16* Bs = smem + 5120;
    int b = blockIdx.z;
    const u16* A = (b == 0) ? xT
                 : (b == B_ - 1) ? (xT + (size_t)(B_ - 1) * FD * INC)
                 : (newT + (size_t)(b - 1) * FD * INC);
    int n0 = blockIdx.x * 64, m0 = blockIdx.y * 128;
    int tid = threadIdx.x, w = tid >> 6, lane = tid & 63, l15 = lane & 15, quad = lane >> 4;
    int sm = tid >> 2, sq = (tid & 3) * 8;
    floatx4 acc[2][4];
    #pragma unroll
    for (int i = 0; i < 2; ++i)
        #pragma unroll
        for (int j = 0; j < 4; ++j) acc[i][j] = (floatx4){0.f,0.f,0.f,0.f};
    for (int k0 = 0; k0 < INC; k0 += 32) {
        *(uint4*)&As[sm * 40 + sq] = *(const uint4*)&A[(size_t)(m0 + sm) * INC + k0 + sq];
        *(uint4*)&As[(64 + sm) * 40 + sq] = *(const uint4*)&A[(size_t)(m0 + 64 + sm) * INC + k0 + sq];
        *(uint4*)&Bs[sm * 40 + sq] = *(const uint4*)&upwT[(size_t)(n0 + sm) * INC + k0 + sq];
        __syncthreads();
        shortx8 bfr[4];
        #pragma unroll
        for (int nt = 0; nt < 4; ++nt)
            bfr[nt] = *(const shortx8*)&Bs[(nt * 16 + l15) * 40 + quad * 8];
        #pragma unroll
        for (int mt = 0; mt < 2; ++mt) {
            shortx8 af = *(const shortx8*)&As[(w * 32 + mt * 16 + l15) * 40 + quad * 8];
            #pragma unroll
            for (int nt = 0; nt < 4; ++nt)
                acc[mt][nt] = __builtin_amdgcn_mfma_f32_16x16x32_bf16(af, bfr[nt], acc[mt][nt], 0, 0, 0);
        }
        __syncthreads();
    }
    u16* Ts = smem;
    int ppos = (l15 & 3) * 128;
    #pragma unroll
    for (int mt = 0; mt < 2; ++mt)
        #pragma unroll
        for (int nt = 0; nt < 4; ++nt) {
            int lm = nt * 16 + l15;
            float bias = up_b[(n0 + lm) >> 2];
            int o_rel = lm >> 2;
            #pragma unroll
            for (int r = 0; r < 4; ++r) {
                int l = w * 32 + mt * 16 + quad * 4 + r;
                Ts[(ppos + l) * 24 + o_rel] = f2bf(acc[mt][nt][r] + bias);
            }
        }
    __syncthreads();
    #pragma unroll
    for (int j2 = 0; j2 < 2; ++j2) {
        int pi = tid + j2 * 256;
        int pp = pi >> 7, l = pi & 127;
        int aa = pp >> 1, cbb = pp & 1;
        int px = m0 + l;
        int row = 2 * (px >> 5) + aa, colq = 2 * (px & 31) + cbb;
        size_t dst = ((size_t)(b * 66 + 1 + row) * 66 + 1 + colq) * 512 + (n0 >> 2);
        union { uint4 v; u16 h[8]; } a0, a1, s0, s1, g0, g1;
        a0.v = *(const uint4*)&Ts[pi * 24];
        a1.v = *(const uint4*)&Ts[pi * 24 + 8];
        s0.v = *(const uint4*)(P + dst + 256);
        s1.v = *(const uint4*)(P + dst + 256 + 8);
        #pragma unroll
        for (int e = 0; e < 8; ++e) {
            float r0 = fmaxf(bf2f(a0.h[e]) + bf2f(s0.h[e]), 0.0f);
            float r1 = fmaxf(bf2f(a1.h[e]) + bf2f(s1.h[e]), 0.0f);
            g0.h[e] = f2bf(1.0f / (1.0f + expf(-r0)));
            g1.h[e] = f2bf(1.0f / (1.0f + expf(-r1)));
        }
        *(uint4*)(P + dst) = g0.v;
        *(uint4*)(P + dst + 8) = g1.v;
    }
}

// ---------------- K4b: skip s -> bf16 into padded P (channels 256..511)
__global__ __launch_bounds__(256) void k4b_sfill(const float* __restrict__ s_in,
                                                 u16* __restrict__ P) {
    __shared__ u16 T[64 * 264];
    int p = blockIdx.x;
    int b = blockIdx.y;
    int tid = threadIdx.x;
    int qcol = tid & 63;
    int ob = tid >> 6;
    for (int o = ob; o < 256; o += 4) {
        float v = s_in[((size_t)(b * OUTC + o) * HO + p) * WO + qcol];
        T[qcol * 264 + o] = f2bf(v);
    }
    __syncthreads();
    int q2 = tid >> 2;
    int sg = tid & 3;
    size_t base = ((size_t)(b * 66 + 1 + p) * 66 + 1 + q2) * 512 + 256;
    #pragma unroll
    for (int it = 0; it < 8; ++it) {
        int seg = sg + it * 4;
        uint4 v = *(const uint4*)&T[q2 * 264 + seg * 8];
        *(uint4*)(P + base + seg * 8) = v;
    }
}

// ---------------- K5: conv3x3 MFMA implicit GEMM.
// Pad-40 X slab staged by global_load_lds (5 slots/pixel, slot 4 dummy);
// weights pipelined one tap ahead in registers; float4 y stores.
__global__ __launch_bounds__(256) void k5_mfma(const u16* __restrict__ P,
        const u16* __restrict__ Wt, const float* __restrict__ c1_b,
        float* __restrict__ y) {
    __shared__ u16 Xs[6 * 66 * KC5P];   // 15840 u16 = 31680 B
    int rb = blockIdx.x;
    int o0 = blockIdx.y * 64;
    int b  = blockIdx.z;
    int tid = threadIdx.x;
    int w = tid >> 6, lane = tid & 63;
    int l15 = lane & 15, quad = lane >> 4;

    floatx4 acc[4][4];
    #pragma unroll
    for (int i = 0; i < 4; ++i)
        #pragma unroll
        for (int j = 0; j < 4; ++j)
            acc[i][j] = (floatx4){0.f, 0.f, 0.f, 0.f};

    size_t Pbase = ((size_t)b * 66 + (size_t)rb * 4) * 66 * 512;   // 396 contiguous pixels
    const u16* Wbase = Wt + ((size_t)o0 + (size_t)l15) * 512 + quad * 8;

    for (int ch = 0; ch < 16; ++ch) {
        int c0 = ch * 32;
        __syncthreads();
        // stage: 1980 slots of 16B. slot s -> pixel s/5, cs = s%5 (cs==4 dummy, never read)
        #pragma unroll
        for (int it = 0; it < 8; ++it) {
            int s = it * 256 + tid;
            if (s < 1980) {
                int pix = s / 5;
                int cs = s - pix * 5;
                int csel = (cs == 4) ? 0 : cs;
                const u16* gp = P + Pbase + (size_t)pix * 512 + c0 + csel * 8;
                __builtin_amdgcn_global_load_lds(
                    (const __attribute__((address_space(1))) void*)gp,
                    (__attribute__((address_space(3))) void*)&Xs[(size_t)(it * 256 + w * 64) * 8],
                    16, 0, 0);
            }
        }
        __syncthreads();
        // tap-pipelined MFMA: load tap+1 weights while computing tap
        shortx8 wfb[2][4];
        #pragma unroll
        for (int nt = 0; nt < 4; ++nt)
            wfb[0][nt] = *(const shortx8*)(Wbase + ((size_t)nt * 16) * 512 + c0);
        #pragma unroll
        for (int tap = 0; tap < 9; ++tap) {
            if (tap < 8) {
                #pragma unroll
                for (int nt = 0; nt < 4; ++nt)
                    wfb[(tap + 1) & 1][nt] = *(const shortx8*)(Wbase +
                        ((size_t)(tap + 1) * 256 + (size_t)nt * 16) * 512 + c0);
            }
            int dy = tap / 3, dx = tap - dy * 3;
            #pragma unroll
            for (int mt = 0; mt < 4; ++mt) {
                shortx8 af = *(const shortx8*)&Xs[((w + dy) * 66 + mt * 16 + l15 + dx) * KC5P + quad * 8];
                #pragma unroll
                for (int nt = 0; nt < 4; ++nt)
                    acc[mt][nt] = __builtin_amdgcn_mfma_f32_16x16x32_bf16(
                        af, wfb[tap & 1][nt], acc[mt][nt], 0, 0, 0);
            }
        }
    }
    int row = rb * 4 + w;
    float bias[4];
    #pragma unroll
    for (int nt = 0; nt < 4; ++nt) bias[nt] = c1_b[o0 + nt * 16 + l15];
    #pragma unroll
    for (int mt = 0; mt < 4; ++mt) {
        #pragma unroll
        for (int nt = 0; nt < 4; ++nt) {
            int o = o0 + nt * 16 + l15;
            size_t ybase = (size_t)(b * OUTC + o) * SP + row * 64;
            float4 v;
            v.x = acc[mt][nt][0] + bias[nt];
            v.y = acc[mt][nt][1] + bias[nt];
            v.z = acc[mt][nt][2] + bias[nt];
            v.w = acc[mt][nt][3] + bias[nt];
            *(float4*)&y[ybase + mt * 16 + quad * 4] = v;
        }
    }
}

// ---------------- K6: BN stats reduce
__global__ __launch_bounds__(256) void k6_bnred(const float* __restrict__ y,
        float* __restrict__ bnsum, float* __restrict__ bnsq) {
    int b = blockIdx.x, o = blockIdx.y;
    const float* p = y + ((size_t)b * OUTC + o) * SP;
    float s1 = 0.f, s2 = 0.f;
    for (int i = threadIdx.x; i < SP; i += 256) { float v = p[i]; s1 += v; s2 = fmaf(v, v, s2); }
    #pragma unroll
    for (int off = 32; off > 0; off >>= 1) {
        s1 += __shfl_down(s1, off, 64);
        s2 += __shfl_down(s2, off, 64);
    }
    __shared__ float r1[4], r2[4];
    int wid = threadIdx.x >> 6, lane = threadIdx.x & 63;
    if (lane == 0) { r1[wid] = s1; r2[wid] = s2; }
    __syncthreads();
    if (threadIdx.x == 0) {
        atomicAdd(&bnsum[o], r1[0] + r1[1] + r1[2] + r1[3]);
        atomicAdd(&bnsq[o],  r2[0] + r2[1] + r2[2] + r2[3]);
    }
}

// ---------------- K7: BN finalize
__global__ void k7_bnfin(const float* __restrict__ bnsum, const float* __restrict__ bnsq,
                         const float* __restrict__ bn_g, const float* __restrict__ bn_b,
                         float* __restrict__ scale, float* __restrict__ shift) {
    int o = threadIdx.x;
    float cnt = (float)(B_ * SP);
    float mu = bnsum[o] / cnt;
    float var = bnsq[o] / cnt - mu * mu;
    float sc = bn_g[o] * rsqrtf(var + 1e-5f);
    scale[o] = sc;
    shift[o] = bn_b[o] - mu * sc;
}

// ---------------- K8: BN apply + relu
__global__ __launch_bounds__(256) void k8_apply(float* __restrict__ y,
        const float* __restrict__ scale, const float* __restrict__ shift) {
    int i = blockIdx.x * 256 + threadIdx.x;
    int o = (i >> 10) & 255;
    float4 v = ((float4*)y)[i];
    float sc = scale[o], sh = shift[o];
    v.x = fmaxf(fmaf(v.x, sc, sh), 0.f);
    v.y = fmaxf(fmaf(v.y, sc, sh), 0.f);
    v.z = fmaxf(fmaf(v.z, sc, sh), 0.f);
    v.w = fmaxf(fmaf(v.w, sc, sh), 0.f);
    ((float4*)y)[i] = v;
}

extern "C" void kernel_launch(void* const* d_in, const int* in_sizes, int n_in,
                              void* d_out, int out_size, void* d_ws, size_t ws_size,
                              hipStream_t stream) {
    const float* x    = (const float*)d_in[0];
    const float* s_in = (const float*)d_in[1];
    const float* up_w = (const float*)d_in[2];
    const float* up_b = (const float*)d_in[3];
    const float* wq   = (const float*)d_in[4];
    const float* wkl  = (const float*)d_in[5];
    const float* wkr  = (const float*)d_in[6];
    const float* c1_w = (const float*)d_in[7];
    const float* c1_b = (const float*)d_in[8];
    const float* bn_g = (const float*)d_in[9];
    const float* bn_b = (const float*)d_in[10];
    float* y = (float*)d_out;
    float* ws = (float*)d_ws;

    size_t off = 0;
    float* bnsum = ws + off; off += OUTC;
    float* bnsq  = ws + off; off += OUTC;
    float* ksuml = ws + off; off += (size_t)T_ * DK;
    float* ksumr = ws + off; off += (size_t)T_ * DK;
    float* zl    = ws + off; off += (size_t)T_ * INC;
    float* zr    = ws + off; off += (size_t)T_ * INC;
    float* scale = ws + off; off += OUTC;
    float* shift = ws + off; off += OUTC;

    u16* ub = (u16*)(ws + off);
    size_t uo = 0;
    u16* qb   = ub + uo; uo += (size_t)T_ * INC * DK;
    u16* klt  = ub + uo; uo += (size_t)T_ * DK * INC;
    u16* krt  = ub + uo; uo += (size_t)T_ * DK * INC;
    u16* kvlT = ub + uo; uo += (size_t)T_ * FD * DK;
    u16* kvrT = ub + uo; uo += (size_t)T_ * FD * DK;
    u16* newT = ub + uo; uo += (size_t)T_ * FD * INC;
    u16* xT   = ub + uo; uo += (size_t)B_ * FD * INC;
    u16* wqT  = ub + uo; uo += (size_t)DK * FD;
    u16* wklT = ub + uo; uo += (size_t)DK * FD;
    u16* wkrT = ub + uo; uo += (size_t)DK * FD;
    u16* upwT = ub + uo; uo += (size_t)FD * INC;
    u16* Wt   = ub + uo; uo += (size_t)9 * OUTC * 2 * INC;
    u16* P    = ub + uo; uo += (size_t)B_ * 66 * 66 * 512;

    // zero bnsum, bnsq, ksuml, ksumr (contiguous)
    hipMemsetAsync(bnsum, 0, (2 * OUTC + 2 * T_ * DK) * sizeof(float), stream);

    kborder<<<dim3(13, B_), dim3(256), 0, stream>>>(P);
    kprep_x<<<dim3(16, 8, B_), dim3(256), 0, stream>>>(x, xT);
    ktr_w<<<dim3(2, 16), dim3(256), 0, stream>>>(wq, wqT, FD, DK);
    ktr_w<<<dim3(2, 16), dim3(256), 0, stream>>>(wkl, wklT, FD, DK);
    ktr_w<<<dim3(2, 16), dim3(256), 0, stream>>>(wkr, wkrT, FD, DK);
    ktr_w<<<dim3(16, 8), dim3(256), 0, stream>>>(up_w, upwT, INC, FD);
    kw_tr<<<dim3((256 * 512 * 9 + 255) / 256), dim3(256), 0, stream>>>(c1_w, Wt);

    k1_proj<<<dim3(2, 4, 42), dim3(256), 0, stream>>>(x, wqT, wklT, wkrT, qb, klt, krt);
    k2b_ksum<<<dim3(T_, 8), dim3(128), 0, stream>>>(klt, krt, ksuml, ksumr);
    k2c_z<<<dim3(T_), dim3(512), 0, stream>>>(qb, ksuml, ksumr, zl, zr);
    k2_kv<<<dim3(2, 8, 28), dim3(256), 0, stream>>>(xT, klt, krt, kvlT, kvrT);
    k3_out<<<dim3(8, 8, T_), dim3(256), 0, stream>>>(xT, qb, kvlT, kvrT, zl, zr, newT);
    k4b_sfill<<<dim3(64, B_), dim3(256), 0, stream>>>(s_in, P);
    k4_up<<<dim3(16, 8, B_), dim3(256), 0, stream>>>(xT, newT, upwT, up_b, P);
    k5_mfma<<<dim3(16, 4, B_), dim3(256), 0, stream>>>(P, Wt, c1_b, y);
    k6_bnred<<<dim3(B_, OUTC), dim3(256), 0, stream>>>(y, bnsum, bnsq);
    k7_bnfin<<<dim3(1), dim3(OUTC), 0, stream>>>(bnsum, bnsq, bn_g, bn_b, scale, shift);
    k8_apply<<<dim3((B_ * OUTC * SP / 4) / 256), dim3(256), 0, stream>>>(y, scale, shift);
}